// Round 20
// baseline (356.657 us; speedup 1.0000x reference)
//
#include <hip/hip_runtime.h>
#include <stdint.h>

// ---------- types ----------
typedef unsigned short ushort_t;
typedef __bf16 bf16x8 __attribute__((ext_vector_type(8)));
typedef float f32x4 __attribute__((ext_vector_type(4)));
typedef float float4v __attribute__((ext_vector_type(4)));
typedef unsigned short ushort4v __attribute__((ext_vector_type(4)));

#define T_SEQ 2048
#define D_MODEL 2048
#define N_HEADS 16
#define HEAD_D 128
#define BATCH 2
#define M_ROWS (BATCH * T_SEQ)   // 4096

__device__ __forceinline__ ushort_t f2bf(float f) {
    unsigned u = __builtin_bit_cast(unsigned, f);
    u += 0x7fffu + ((u >> 16) & 1u);   // RNE
    return (ushort_t)(u >> 16);
}
__device__ __forceinline__ float bf2f(ushort_t h) {
    unsigned u = ((unsigned)h) << 16;
    return __builtin_bit_cast(float, u);
}

__device__ __forceinline__ void gload16(const ushort_t* g, ushort_t* l) {
    __builtin_amdgcn_global_load_lds(
        (const __attribute__((address_space(1))) void*)g,
        (__attribute__((address_space(3))) void*)l,
        16, 0, 0);
}

#define SBAR0() __builtin_amdgcn_sched_barrier(0)

// ---------- fused prep (R17 exact) ----------
__global__ __launch_bounds__(256) void prep_kernel(
    const float* __restrict__ x, ushort_t* __restrict__ xb,
    const float* __restrict__ W_qkv, const float* __restrict__ W_gate,
    const float* __restrict__ W_out,
    ushort_t* __restrict__ wqgT, ushort_t* __restrict__ woutT)
{
    const int bid = blockIdx.x;
    if (bid < 8192) {
        int i = bid * 256 + threadIdx.x;
        float4v v = *(const float4v*)(x + (size_t)i * 4);
        ushort4v o;
        o[0] = f2bf(v[0]); o[1] = f2bf(v[1]); o[2] = f2bf(v[2]); o[3] = f2bf(v[3]);
        *(ushort4v*)(xb + (size_t)i * 4) = o;
        return;
    }
    __shared__ float tile[32][33];
    int tix = bid - 8192;
    const float* W; ushort_t* Wt; int Ncols, tnx;
    if (tix < 192 * 64) {
        W = W_qkv; Wt = wqgT; Ncols = 3 * D_MODEL; tnx = tix % 192;
    } else if (tix < 192 * 64 + 64 * 64) {
        tix -= 192 * 64;
        W = W_gate; Wt = wqgT + (size_t)3 * D_MODEL * D_MODEL; Ncols = D_MODEL; tnx = tix % 64;
    } else {
        tix -= 192 * 64 + 64 * 64;
        W = W_out; Wt = woutT; Ncols = D_MODEL; tnx = tix % 64;
    }
    int n0 = tnx * 32, k0 = (tix / ((W == W_qkv) ? 192 : 64)) * 32;
    int tx = threadIdx.x & 31, ty = threadIdx.x >> 5;
#pragma unroll
    for (int i = 0; i < 4; ++i)
        tile[ty + i * 8][tx] = W[(size_t)(k0 + ty + i * 8) * Ncols + n0 + tx];
    __syncthreads();
#pragma unroll
    for (int i = 0; i < 4; ++i)
        Wt[(size_t)(n0 + ty + i * 8) * D_MODEL + k0 + tx] = f2bf(tile[tx][ty + i * 8]);
}

// ================= shared 8-phase 256x256 GEMM engine (R15/R17 proven) =================
// EPI 0: QKV+gate scatter (N=8192). EPI 1: f32 row-major C (N=2048, out GEMM).
// Session record rate: 722 TF. launch_bounds(512,2) required (R18: 4 waves/SIMD
// spills the ~200-reg accumulator working set to scratch - 5x regression).
template <int EPI>
__global__ __launch_bounds__(512, 2) void gemm256(
    const ushort_t* __restrict__ A, const ushort_t* __restrict__ Bt,
    ushort_t* __restrict__ o_q, ushort_t* __restrict__ o_k, ushort_t* __restrict__ o_vt,
    const float* __restrict__ b_gate, ushort_t* __restrict__ o_g,
    float* __restrict__ o_f32)
{
    const int K = D_MODEL;                  // 2048
    __shared__ ushort_t Al[2][16384];       // 64 KB
    __shared__ ushort_t Bl[2][16384];       // 64 KB
    const int tid = threadIdx.x;
    const int l = tid & 63;
    const int ln = l & 15, hi = l >> 4;
    const int lnx = (ln & 7) << 4;
    const int wid = tid >> 6;               // 0..7
    const int wm = wid >> 2, wn = wid & 3;  // 2m x 4n

    // XCD regions (bijective):
    //  EPI 0: 16m x 32n tiles -> 8 regions (2x4) of 8m x 8n
    //  EPI 1: 16m x 8n tiles  -> 8 regions (2x4) of 8m x 2n
    const int lin = blockIdx.x;
    const int r = lin & 7, w = lin >> 3;
    int bm, bn;
    if (EPI == 0) { bm = (r >> 2) * 8 + (w >> 3); bn = (r & 3) * 8 + (w & 7); }
    else          { bm = (r >> 2) * 8 + (w >> 1); bn = (r & 3) * 2 + (w & 1); }
    const int m0 = bm * 256, n0 = bn * 256;

    f32x4 acc[8][4];
#pragma unroll
    for (int mm = 0; mm < 8; ++mm)
#pragma unroll
        for (int nn = 0; nn < 4; ++nn) acc[mm][nn] = (f32x4){0.f, 0.f, 0.f, 0.f};

    const ushort_t* As_0[2]; const ushort_t* As_1[2];
    const ushort_t* Bs_0[2]; const ushort_t* Bs_1[2];
    int dst_[2];
#pragma unroll
    for (int i = 0; i < 2; ++i) {
        int c = i * 512 + tid;
        int row = c >> 3;
        int sc = ((c & 7) ^ (row & 7)) << 3;
        As_0[i] = A + (size_t)(m0 + row) * K + sc;
        As_1[i] = A + (size_t)(m0 + 128 + row) * K + sc;
        Bs_0[i] = Bt + (size_t)(n0 + row) * K + sc;
        Bs_1[i] = Bt + (size_t)(n0 + 128 + row) * K + sc;
        dst_[i] = i * 4096 + wid * 512;
    }

#define STG_A(pq, kt) { _Pragma("unroll") for (int i_ = 0; i_ < 2; ++i_) {     \
        gload16(As_0[i_] + ((kt) << 6), Al[pq] + dst_[i_]);                    \
        gload16(As_1[i_] + ((kt) << 6), Al[pq] + 8192 + dst_[i_]); } }
#define STG_B(pq, kt) { _Pragma("unroll") for (int i_ = 0; i_ < 2; ++i_) {     \
        gload16(Bs_0[i_] + ((kt) << 6), Bl[pq] + dst_[i_]);                    \
        gload16(Bs_1[i_] + ((kt) << 6), Bl[pq] + 8192 + dst_[i_]); } }

#define RDA(P, mm_, kk_) (*(const bf16x8*)((const char*)Al[P] + (wm << 14) +   \
        ((((mm_) << 4) + ln) << 7) + ((((kk_) << 6) + (hi << 4)) ^ lnx)))
#define RDB(P, nn_, kk_) (*(const bf16x8*)((const char*)Bl[P] + ((wn >> 1) << 14) + \
        ((((wn & 1) << 6) + ((nn_) << 4) + ln) << 7) + ((((kk_) << 6) + (hi << 4)) ^ lnx)))

#define MFMA16(MLO) { _Pragma("unroll") for (int mm = 0; mm < 4; ++mm)         \
        _Pragma("unroll") for (int nn = 0; nn < 4; ++nn)                       \
        acc[(MLO) + mm][nn] = __builtin_amdgcn_mfma_f32_16x16x32_bf16(         \
            af[mm], bfg[nn], acc[(MLO) + mm][nn], 0, 0, 0); }

#define LGKM0() { asm volatile("s_waitcnt lgkmcnt(0)" ::: "memory"); SBAR0(); }
#define BAR() __builtin_amdgcn_s_barrier()

    STG_A(0, 0); STG_B(0, 0);
    STG_A(1, 1); STG_B(1, 1);
    asm volatile("s_waitcnt vmcnt(8)" ::: "memory");
    BAR();

    const int NIT = K >> 7;                 // 16 iterations x 2 K-tiles
    for (int it = 0; it < NIT; ++it) {
        const bool nf = (it + 1 < NIT);
        bf16x8 bfg[4];
        { // ph0
            if (it > 0) STG_A(1, 2 * it + 1);
            bf16x8 af[4];
            af[0] = RDA(0, 0, 0); af[1] = RDA(0, 1, 0); af[2] = RDA(0, 2, 0); af[3] = RDA(0, 3, 0);
            bfg[0] = RDB(0, 0, 0); bfg[1] = RDB(0, 1, 0); bfg[2] = RDB(0, 2, 0); bfg[3] = RDB(0, 3, 0);
            BAR(); LGKM0();
            __builtin_amdgcn_s_setprio(1); MFMA16(0); __builtin_amdgcn_s_setprio(0);
            BAR();
        }
        { // ph1
            bf16x8 af[4];
            af[0] = RDA(0, 4, 0); af[1] = RDA(0, 5, 0); af[2] = RDA(0, 6, 0); af[3] = RDA(0, 7, 0);
            BAR(); LGKM0();
            __builtin_amdgcn_s_setprio(1); MFMA16(4); __builtin_amdgcn_s_setprio(0);
            BAR();
        }
        { // ph2
            bf16x8 af[4];
            af[0] = RDA(0, 0, 1); af[1] = RDA(0, 1, 1); af[2] = RDA(0, 2, 1); af[3] = RDA(0, 3, 1);
            bfg[0] = RDB(0, 0, 1); bfg[1] = RDB(0, 1, 1); bfg[2] = RDB(0, 2, 1); bfg[3] = RDB(0, 3, 1);
            BAR(); LGKM0();
            __builtin_amdgcn_s_setprio(1); MFMA16(0); __builtin_amdgcn_s_setprio(0);
            BAR();
        }
        { // ph3
            if (nf) STG_B(0, 2 * it + 2);
            bf16x8 af[4];
            af[0] = RDA(0, 4, 1); af[1] = RDA(0, 5, 1); af[2] = RDA(0, 6, 1); af[3] = RDA(0, 7, 1);
            BAR(); LGKM0();
            __builtin_amdgcn_s_setprio(1); MFMA16(4); __builtin_amdgcn_s_setprio(0);
            if (nf) { asm volatile("s_waitcnt vmcnt(4)" ::: "memory"); }
            else    { asm volatile("s_waitcnt vmcnt(0)" ::: "memory"); }
            BAR();
        }
        { // ph4
            if (nf) STG_A(0, 2 * it + 2);
            bf16x8 af[4];
            af[0] = RDA(1, 0, 0); af[1] = RDA(1, 1, 0); af[2] = RDA(1, 2, 0); af[3] = RDA(1, 3, 0);
            bfg[0] = RDB(1, 0, 0); bfg[1] = RDB(1, 1, 0); bfg[2] = RDB(1, 2, 0); bfg[3] = RDB(1, 3, 0);
            BAR(); LGKM0();
            __builtin_amdgcn_s_setprio(1); MFMA16(0); __builtin_amdgcn_s_setprio(0);
            BAR();
        }
        { // ph5
            bf16x8 af[4];
            af[0] = RDA(1, 4, 0); af[1] = RDA(1, 5, 0); af[2] = RDA(1, 6, 0); af[3] = RDA(1, 7, 0);
            BAR(); LGKM0();
            __builtin_amdgcn_s_setprio(1); MFMA16(4); __builtin_amdgcn_s_setprio(0);
            BAR();
        }
        { // ph6
            bf16x8 af[4];
            af[0] = RDA(1, 0, 1); af[1] = RDA(1, 1, 1); af[2] = RDA(1, 2, 1); af[3] = RDA(1, 3, 1);
            bfg[0] = RDB(1, 0, 1); bfg[1] = RDB(1, 1, 1); bfg[2] = RDB(1, 2, 1); bfg[3] = RDB(1, 3, 1);
            BAR(); LGKM0();
            __builtin_amdgcn_s_setprio(1); MFMA16(0); __builtin_amdgcn_s_setprio(0);
            BAR();
        }
        { // ph7
            if (nf) STG_B(1, 2 * it + 3);
            bf16x8 af[4];
            af[0] = RDA(1, 4, 1); af[1] = RDA(1, 5, 1); af[2] = RDA(1, 6, 1); af[3] = RDA(1, 7, 1);
            BAR(); LGKM0();
            __builtin_amdgcn_s_setprio(1); MFMA16(4); __builtin_amdgcn_s_setprio(0);
            if (nf) { asm volatile("s_waitcnt vmcnt(4)" ::: "memory"); }
            BAR();
        }
    }
#undef STG_A
#undef STG_B
#undef RDA
#undef RDB
#undef MFMA16
#undef LGKM0
#undef BAR

    if (EPI == 0) {
        const int sec = n0 >> 11;
#pragma unroll
        for (int mm = 0; mm < 8; ++mm)
#pragma unroll
            for (int nn = 0; nn < 4; ++nn)
#pragma unroll
                for (int j = 0; j < 4; ++j) {
                    int grow = m0 + wm * 128 + mm * 16 + hi * 4 + j;   // b*T + t
                    int b = grow >> 11, t = grow & 2047;
                    int col = n0 + wn * 64 + nn * 16 + ln;
                    int c2 = col & 2047;
                    int dd = c2 & 127;
                    int h = c2 >> 7;
                    size_t bh = (size_t)(b * N_HEADS + h);
                    if (sec == 0)      o_q[(bh * T_SEQ + t) * HEAD_D + dd] = f2bf(acc[mm][nn][j]);
                    else if (sec == 1) o_k[(bh * T_SEQ + t) * HEAD_D + dd] = f2bf(acc[mm][nn][j]);
                    else if (sec == 2) o_vt[(bh * HEAD_D + dd) * T_SEQ + t] = f2bf(acc[mm][nn][j]);
                    else {
                        float g = acc[mm][nn][j] + b_gate[c2];
                        g = 1.0f / (1.0f + __expf(-g));
                        o_g[(size_t)grow * D_MODEL + c2] = f2bf(g);
                    }
                }
    } else {
#pragma unroll
        for (int mm = 0; mm < 8; ++mm)
#pragma unroll
            for (int nn = 0; nn < 4; ++nn)
#pragma unroll
                for (int j = 0; j < 4; ++j) {
                    int grow = m0 + wm * 128 + mm * 16 + hi * 4 + j;
                    int gcol = n0 + wn * 64 + nn * 16 + ln;
                    o_f32[(size_t)grow * D_MODEL + gcol] = acc[mm][nn][j];
                }
    }
}

// ---------- RMSNorm + RoPE, in place on q and k [B,H,T,128] ----------
__global__ __launch_bounds__(256) void rmsrope_kernel(ushort_t* __restrict__ qb, ushort_t* __restrict__ kb) {
    int wid = threadIdx.x >> 6, l = threadIdx.x & 63;
    int row = blockIdx.x * 4 + wid;          // (b*H + h)*T + t
    int t = row & (T_SEQ - 1);
    size_t base = (size_t)row * HEAD_D;

    float ang = (float)t * expf(-(float)l * 0.14391156f);
    float sv, cv;
    sincosf(ang, &sv, &cv);

    float a = bf2f(qb[base + l]), b = bf2f(qb[base + 64 + l]);
    float ss = a * a + b * b;
#pragma unroll
    for (int d = 1; d < 64; d <<= 1) ss += __shfl_xor(ss, d);
    float r = rsqrtf(ss * (1.0f / 128.0f) + 1e-6f);
    a *= r; b *= r;
    qb[base + l]      = f2bf(a * cv - b * sv);
    qb[base + 64 + l] = f2bf(a * sv + b * cv);

    a = bf2f(kb[base + l]); b = bf2f(kb[base + 64 + l]);
    ss = a * a + b * b;
#pragma unroll
    for (int d = 1; d < 64; d <<= 1) ss += __shfl_xor(ss, d);
    r = rsqrtf(ss * (1.0f / 128.0f) + 1e-6f);
    a *= r; b *= r;
    kb[base + l]      = f2bf(a * cv - b * sv);
    kb[base + 64 + l] = f2bf(a * sv + b * cv);
}

// ---------- causal flash attention v7 (R10..R19 passing version, unchanged) ----------
__global__ __launch_bounds__(256) void flash_kernel(
    const ushort_t* __restrict__ qb, const ushort_t* __restrict__ kb,
    const ushort_t* __restrict__ vt, const ushort_t* __restrict__ g_b,
    ushort_t* __restrict__ y_b)
{
    const int bh = blockIdx.x, bxp = blockIdx.y;
    const int tid = threadIdx.x;
    const int wid = tid >> 6, l = tid & 63;
    const int ln = l & 15, hi = l >> 4;
    const int lnx = (ln & 7) << 4;

    const ushort_t* Q  = qb + (size_t)bh * T_SEQ * HEAD_D;
    const ushort_t* Kp = kb + (size_t)bh * T_SEQ * HEAD_D;
    const ushort_t* Vp = vt + (size_t)bh * HEAD_D * T_SEQ;

    __shared__ ushort_t Ks[4][64 * 128];
    __shared__ ushort_t Vs[4][128 * 64];
    __shared__ ushort_t p_all[4][32][72];
    ushort_t (*p_lds)[72] = p_all[wid];

    const float scale_log2 = 0.12752059520313818f;
    const int bb = bh >> 4, h = bh & 15;

    int s_off[4], s_ksrc[4], s_vrow[4], s_vcol[4];
#pragma unroll
    for (int i = 0; i < 4; ++i) {
        int off = (i * 256 + tid) * 16;
        s_off[i] = (i * 4 + wid) * 512;
        int krow = off >> 8;
        s_ksrc[i] = off ^ ((krow & 7) << 4);
        int vrow = off >> 7;
        s_vrow[i] = vrow;
        s_vcol[i] = ((off & 127) ^ ((vrow & 7) << 4)) >> 1;
    }

#define STAGE(kvbase, Kd, Vd)                                                            \
    {                                                                                    \
        _Pragma("unroll")                                                                \
        for (int i_ = 0; i_ < 4; ++i_) {                                                 \
            gload16((const ushort_t*)((const char*)(Kp + (size_t)(kvbase) * HEAD_D) +    \
                                      s_ksrc[i_]), (Kd) + s_off[i_]);                    \
            gload16(Vp + (size_t)s_vrow[i_] * T_SEQ + (kvbase) + s_vcol[i_],             \
                    (Vd) + s_off[i_]);                                                   \
        }                                                                                \
    }

    for (int pass = 0; pass < 2; ++pass) {
        const int qt = pass ? (15 - bxp) : bxp;
        const int q0w = qt * 128 + wid * 32;
        const int nt = 2 * qt + 2;

        bf16x8 qf[2][4];
#pragma unroll
        for (int m = 0; m < 2; ++m)
#pragma unroll
            for (int kk = 0; kk < 4; ++kk)
                qf[m][kk] = *(const bf16x8*)(Q + (size_t)(q0w + m * 16 + ln) * HEAD_D + kk * 32 + hi * 8);

        f32x4 acc_o[2][8];
#pragma unroll
        for (int m = 0; m < 2; ++m)
#pragma unroll
            for (int nd = 0; nd < 8; ++nd) acc_o[m][nd] = (f32x4){0.f, 0.f, 0.f, 0.f};
        float rl[2][4];
#pragma unroll
        for (int m = 0; m < 2; ++m)
#pragma unroll
            for (int j = 0; j < 4; ++j) rl[m][j] = 0.f;

        ushort_t *Ka = Ks[0], *Kb = Ks[1], *Kc = Ks[2], *Kd4 = Ks[3];
        ushort_t *Va = Vs[0], *Vb = Vs[1], *Vc = Vs[2], *Vd4 = Vs[3];

        STAGE(0, Ka, Va);
        STAGE(64, Kb, Vb);

        for (int t = 0; t < nt; ++t) {
            const int kv0 = t * 64;
            if (t + 2 < nt) {
                STAGE(kv0 + 128, Kc, Vc);
                asm volatile("s_waitcnt vmcnt(16)" ::: "memory");
            } else if (t + 1 < nt) {
                asm volatile("s_waitcnt vmcnt(8)" ::: "memory");
            } else {
                asm volatile("s_waitcnt vmcnt(0)" ::: "memory");
            }
            SBAR0();
            __builtin_amdgcn_s_barrier();
            SBAR0();

            if (kv0 <= q0w + 31) {
                const ushort_t* Ksc = Ka;
                const ushort_t* Vsc = Va;

                f32x4 sa[2][4];
#pragma unroll
                for (int m = 0; m < 2; ++m)
#pragma unroll
                    for (int n = 0; n < 4; ++n) sa[m][n] = (f32x4){0.f, 0.f, 0.f, 0.f};
#pragma unroll
                for (int kk = 0; kk < 4; ++kk) {
                    bf16x8 kf[4];
#pragma unroll
                    for (int n = 0; n < 4; ++n)
                        kf[n] = *(const bf16x8*)((const char*)Ksc +
                                 ((((n * 16 + ln) << 8) + (kk << 6) + (hi << 4)) ^ lnx));
#pragma unroll
                    for (int m = 0; m < 2; ++m)
#pragma unroll
                        for (int n = 0; n < 4; ++n)
                            sa[m][n] = __builtin_amdgcn_mfma_f32_16x16x32_bf16(qf[m][kk], kf[n], sa[m][n], 0, 0, 0);
                }

                const bool partial = (kv0 + 63 > q0w);
                if (partial) {
#pragma unroll
                    for (int m = 0; m < 2; ++m)
#pragma unroll
                        for (int n = 0; n < 4; ++n)
#pragma unroll
                            for (int j = 0; j < 4; ++j) {
                                int kv = kv0 + n * 16 + ln;
                                int qrow = q0w + m * 16 + hi * 4 + j;
                                float v = (kv <= qrow) ? sa[m][n][j] * scale_log2 : -1e30f;
                                float p = __builtin_amdgcn_exp2f(v);
                                rl[m][j] += p;
                                p_lds[m * 16 + hi * 4 + j][n * 16 + ln] = f2bf(p);
                            }
                } else {
#pragma unroll
                    for (int m = 0; m < 2; ++m)
#pragma unroll
                        for (int n = 0; n < 4; ++n)
#pragma unroll
                            for (int j = 0; j < 4; ++j) {
                                float p = __builtin_amdgcn_exp2f(sa[m][n][j] * scale_log2);
                                rl[m][j] += p;
                                p_lds[m * 16 + hi * 4 + j][n * 16 + ln] = f2bf(p);
                            }
                }
                asm volatile("s_waitcnt lgkmcnt(0)" ::: "memory");
                SBAR0();

                const bool skipB = (kv0 + 32 > q0w + 31);
                bf16x8 pf[2][2];
#pragma unroll
                for (int m = 0; m < 2; ++m)
#pragma unroll
                    for (int kk2 = 0; kk2 < 2; ++kk2)
                        pf[m][kk2] = *(const bf16x8*)(&p_lds[m * 16 + ln][kk2 * 32 + hi * 8]);
#pragma unroll
                for (int nd = 0; nd < 8; ++nd) {
                    bf16x8 vf = *(const bf16x8*)((const char*)Vsc +
                                 ((((nd * 16 + ln) << 7) + (hi << 4)) ^ lnx));
                    acc_o[0][nd] = __builtin_amdgcn_mfma_f32_16x16x32_bf16(pf[0][0], vf, acc_o[0][nd], 0, 0, 0);
                    acc_o[1][nd] = __builtin_amdgcn_mfma_f32_16x16x32_bf16(pf[1][0], vf, acc_o[1][nd], 0, 0, 0);
                }
                if (!skipB) {
#pragma unroll
                    for (int nd = 0; nd < 8; ++nd) {
                        bf16x8 vf = *(const bf16x8*)((const char*)Vsc +
                                     ((((nd * 16 + ln) << 7) + 64 + (hi << 4)) ^ lnx));
                        acc_o[0][nd] = __builtin_amdgcn_mfma_f32_16x16x32_bf16(pf[0][1], vf, acc_o[0][nd], 0, 0, 0);
                        acc_o[1][nd] = __builtin_amdgcn_mfma_f32_16x16x32_bf16(pf[1][1], vf, acc_o[1][nd], 0, 0, 0);
                    }
                }
            }
            asm volatile("s_waitcnt lgkmcnt(0)" ::: "memory");
            SBAR0();
            __builtin_amdgcn_s_barrier();
            SBAR0();
            ushort_t* tK = Ka; Ka = Kb; Kb = Kc; Kc = Kd4; Kd4 = tK;
            ushort_t* tV = Va; Va = Vb; Vb = Vc; Vc = Vd4; Vd4 = tV;
        }

#pragma unroll
        for (int d = 1; d < 16; d <<= 1)
#pragma unroll
            for (int m = 0; m < 2; ++m)
#pragma unroll
                for (int j = 0; j < 4; ++j)
                    rl[m][j] += __shfl_xor(rl[m][j], d);

#pragma unroll
        for (int m = 0; m < 2; ++m)
#pragma unroll
            for (int j = 0; j < 4; ++j) {
                float inv = 1.0f / rl[m][j];
                int tr = q0w + m * 16 + hi * 4 + j;
#pragma unroll
                for (int nd = 0; nd < 8; ++nd) {
                    size_t idx = ((size_t)(bb * T_SEQ + tr)) * D_MODEL + h * HEAD_D + nd * 16 + ln;
                    y_b[idx] = f2bf(acc_o[m][nd][j] * inv * bf2f(g_b[idx]));
                }
            }
    }
#undef STAGE
}

// ---------- launch ----------
extern "C" void kernel_launch(void* const* d_in, const int* in_sizes, int n_in,
                              void* d_out, int out_size, void* d_ws, size_t ws_size,
                              hipStream_t stream) {
    const float* x      = (const float*)d_in[0];
    const float* W_qkv  = (const float*)d_in[1];
    const float* W_out  = (const float*)d_in[2];
    const float* W_gate = (const float*)d_in[3];
    const float* b_gate = (const float*)d_in[4];
    float* out = (float*)d_out;

    char* ws = (char*)d_ws;
    size_t off = 0;
    ushort_t* xb     = (ushort_t*)(ws + off); off += (size_t)M_ROWS * D_MODEL * 2;
    ushort_t* wqgT   = (ushort_t*)(ws + off); off += (size_t)4 * D_MODEL * D_MODEL * 2;
    ushort_t* woutT  = (ushort_t*)(ws + off); off += (size_t)D_MODEL * D_MODEL * 2;
    ushort_t* q_b    = (ushort_t*)(ws + off); off += (size_t)M_ROWS * D_MODEL * 2;
    ushort_t* k_b    = (ushort_t*)(ws + off); off += (size_t)M_ROWS * D_MODEL * 2;
    ushort_t* v_t    = (ushort_t*)(ws + off); off += (size_t)M_ROWS * D_MODEL * 2;
    ushort_t* g_b    = (ushort_t*)(ws + off); off += (size_t)M_ROWS * D_MODEL * 2;
    ushort_t* y_b    = (ushort_t*)(ws + off); off += (size_t)M_ROWS * D_MODEL * 2;

    prep_kernel<<<8192 + 192 * 64 + 64 * 64 + 64 * 64, 256, 0, stream>>>(
        x, xb, W_qkv, W_gate, W_out, wqgT, woutT);
    gemm256<0><<<512, 512, 0, stream>>>(xb, wqgT, q_b, k_b, v_t, b_gate, g_b, nullptr);
    rmsrope_kernel<<<16384, 256, 0, stream>>>(q_b, k_b);
    flash_kernel<<<dim3(32, 8), 256, 0, stream>>>(q_b, k_b, v_t, g_b, y_b);
    gemm256<1><<<128, 512, 0, stream>>>(y_b, woutT, nullptr, nullptr, nullptr, nullptr, nullptr, out);
}

// Round 21
// 329.130 us; speedup vs baseline: 1.0836x; 1.0836x over previous
//
#include <hip/hip_runtime.h>
#include <stdint.h>

// ---------- types ----------
typedef unsigned short ushort_t;
typedef __bf16 bf16x8 __attribute__((ext_vector_type(8)));
typedef float f32x4 __attribute__((ext_vector_type(4)));
typedef float float4v __attribute__((ext_vector_type(4)));
typedef unsigned short ushort4v __attribute__((ext_vector_type(4)));

#define T_SEQ 2048
#define D_MODEL 2048
#define N_HEADS 16
#define HEAD_D 128
#define BATCH 2
#define M_ROWS (BATCH * T_SEQ)   // 4096

__device__ __forceinline__ ushort_t f2bf(float f) {
    unsigned u = __builtin_bit_cast(unsigned, f);
    u += 0x7fffu + ((u >> 16) & 1u);   // RNE
    return (ushort_t)(u >> 16);
}
__device__ __forceinline__ float bf2f(ushort_t h) {
    unsigned u = ((unsigned)h) << 16;
    return __builtin_bit_cast(float, u);
}

__device__ __forceinline__ void gload16(const ushort_t* g, ushort_t* l) {
    __builtin_amdgcn_global_load_lds(
        (const __attribute__((address_space(1))) void*)g,
        (__attribute__((address_space(3))) void*)l,
        16, 0, 0);
}

#define SBAR0() __builtin_amdgcn_sched_barrier(0)

// ---------- fused prep (R17 exact) ----------
__global__ __launch_bounds__(256) void prep_kernel(
    const float* __restrict__ x, ushort_t* __restrict__ xb,
    const float* __restrict__ W_qkv, const float* __restrict__ W_gate,
    const float* __restrict__ W_out,
    ushort_t* __restrict__ wqgT, ushort_t* __restrict__ woutT)
{
    const int bid = blockIdx.x;
    if (bid < 8192) {
        int i = bid * 256 + threadIdx.x;
        float4v v = *(const float4v*)(x + (size_t)i * 4);
        ushort4v o;
        o[0] = f2bf(v[0]); o[1] = f2bf(v[1]); o[2] = f2bf(v[2]); o[3] = f2bf(v[3]);
        *(ushort4v*)(xb + (size_t)i * 4) = o;
        return;
    }
    __shared__ float tile[32][33];
    int tix = bid - 8192;
    const float* W; ushort_t* Wt; int Ncols, tnx;
    if (tix < 192 * 64) {
        W = W_qkv; Wt = wqgT; Ncols = 3 * D_MODEL; tnx = tix % 192;
    } else if (tix < 192 * 64 + 64 * 64) {
        tix -= 192 * 64;
        W = W_gate; Wt = wqgT + (size_t)3 * D_MODEL * D_MODEL; Ncols = D_MODEL; tnx = tix % 64;
    } else {
        tix -= 192 * 64 + 64 * 64;
        W = W_out; Wt = woutT; Ncols = D_MODEL; tnx = tix % 64;
    }
    int n0 = tnx * 32, k0 = (tix / ((W == W_qkv) ? 192 : 64)) * 32;
    int tx = threadIdx.x & 31, ty = threadIdx.x >> 5;
#pragma unroll
    for (int i = 0; i < 4; ++i)
        tile[ty + i * 8][tx] = W[(size_t)(k0 + ty + i * 8) * Ncols + n0 + tx];
    __syncthreads();
#pragma unroll
    for (int i = 0; i < 4; ++i)
        Wt[(size_t)(n0 + ty + i * 8) * D_MODEL + k0 + tx] = f2bf(tile[tx][ty + i * 8]);
}

// ---------- QKV+gate GEMM: 256x256, BK=64, 8 waves, 8-phase (R15/R17/R19 exact) ----------
// Session record: 190 µs (722 TF, MfmaUtil 30%, 0 bank conflicts).
// R18: >=2 blocks/CU at 256² spills accumulators (needs launch_bounds(512,2)).
// R20: 256² out-GEMM has only 128 tiles -> half the CUs idle; 128² is right there.
__global__ __launch_bounds__(512, 2) void gemm256_qkvg(
    const ushort_t* __restrict__ A, const ushort_t* __restrict__ Bt,
    ushort_t* __restrict__ o_q, ushort_t* __restrict__ o_k, ushort_t* __restrict__ o_vt,
    const float* __restrict__ b_gate, ushort_t* __restrict__ o_g)
{
    const int K = D_MODEL;                  // 2048
    __shared__ ushort_t Al[2][16384];       // 64 KB
    __shared__ ushort_t Bl[2][16384];       // 64 KB
    const int tid = threadIdx.x;
    const int l = tid & 63;
    const int ln = l & 15, hi = l >> 4;
    const int lnx = (ln & 7) << 4;
    const int wid = tid >> 6;               // 0..7
    const int wm = wid >> 2, wn = wid & 3;  // 2m x 4n

    const int lin = blockIdx.x;
    const int r = lin & 7, w = lin >> 3;
    const int bm = (r >> 2) * 8 + (w >> 3);
    const int bn = (r & 3) * 8 + (w & 7);
    const int m0 = bm * 256, n0 = bn * 256;

    f32x4 acc[8][4];
#pragma unroll
    for (int mm = 0; mm < 8; ++mm)
#pragma unroll
        for (int nn = 0; nn < 4; ++nn) acc[mm][nn] = (f32x4){0.f, 0.f, 0.f, 0.f};

    const ushort_t* As_0[2]; const ushort_t* As_1[2];
    const ushort_t* Bs_0[2]; const ushort_t* Bs_1[2];
    int dst_[2];
#pragma unroll
    for (int i = 0; i < 2; ++i) {
        int c = i * 512 + tid;
        int row = c >> 3;
        int sc = ((c & 7) ^ (row & 7)) << 3;
        As_0[i] = A + (size_t)(m0 + row) * K + sc;
        As_1[i] = A + (size_t)(m0 + 128 + row) * K + sc;
        Bs_0[i] = Bt + (size_t)(n0 + row) * K + sc;
        Bs_1[i] = Bt + (size_t)(n0 + 128 + row) * K + sc;
        dst_[i] = i * 4096 + wid * 512;
    }

#define STG_A(pq, kt) { _Pragma("unroll") for (int i_ = 0; i_ < 2; ++i_) {     \
        gload16(As_0[i_] + ((kt) << 6), Al[pq] + dst_[i_]);                    \
        gload16(As_1[i_] + ((kt) << 6), Al[pq] + 8192 + dst_[i_]); } }
#define STG_B(pq, kt) { _Pragma("unroll") for (int i_ = 0; i_ < 2; ++i_) {     \
        gload16(Bs_0[i_] + ((kt) << 6), Bl[pq] + dst_[i_]);                    \
        gload16(Bs_1[i_] + ((kt) << 6), Bl[pq] + 8192 + dst_[i_]); } }

#define RDA(P, mm_, kk_) (*(const bf16x8*)((const char*)Al[P] + (wm << 14) +   \
        ((((mm_) << 4) + ln) << 7) + ((((kk_) << 6) + (hi << 4)) ^ lnx)))
#define RDB(P, nn_, kk_) (*(const bf16x8*)((const char*)Bl[P] + ((wn >> 1) << 14) + \
        ((((wn & 1) << 6) + ((nn_) << 4) + ln) << 7) + ((((kk_) << 6) + (hi << 4)) ^ lnx)))

#define MFMA16(MLO) { _Pragma("unroll") for (int mm = 0; mm < 4; ++mm)         \
        _Pragma("unroll") for (int nn = 0; nn < 4; ++nn)                       \
        acc[(MLO) + mm][nn] = __builtin_amdgcn_mfma_f32_16x16x32_bf16(         \
            af[mm], bfg[nn], acc[(MLO) + mm][nn], 0, 0, 0); }

#define LGKM0() { asm volatile("s_waitcnt lgkmcnt(0)" ::: "memory"); SBAR0(); }
#define BAR() __builtin_amdgcn_s_barrier()

    STG_A(0, 0); STG_B(0, 0);
    STG_A(1, 1); STG_B(1, 1);
    asm volatile("s_waitcnt vmcnt(8)" ::: "memory");
    BAR();

    const int NIT = K >> 7;                 // 16 iterations x 2 K-tiles
    for (int it = 0; it < NIT; ++it) {
        const bool nf = (it + 1 < NIT);
        bf16x8 bfg[4];
        { // ph0
            if (it > 0) STG_A(1, 2 * it + 1);
            bf16x8 af[4];
            af[0] = RDA(0, 0, 0); af[1] = RDA(0, 1, 0); af[2] = RDA(0, 2, 0); af[3] = RDA(0, 3, 0);
            bfg[0] = RDB(0, 0, 0); bfg[1] = RDB(0, 1, 0); bfg[2] = RDB(0, 2, 0); bfg[3] = RDB(0, 3, 0);
            BAR(); LGKM0();
            __builtin_amdgcn_s_setprio(1); MFMA16(0); __builtin_amdgcn_s_setprio(0);
            BAR();
        }
        { // ph1
            bf16x8 af[4];
            af[0] = RDA(0, 4, 0); af[1] = RDA(0, 5, 0); af[2] = RDA(0, 6, 0); af[3] = RDA(0, 7, 0);
            BAR(); LGKM0();
            __builtin_amdgcn_s_setprio(1); MFMA16(4); __builtin_amdgcn_s_setprio(0);
            BAR();
        }
        { // ph2
            bf16x8 af[4];
            af[0] = RDA(0, 0, 1); af[1] = RDA(0, 1, 1); af[2] = RDA(0, 2, 1); af[3] = RDA(0, 3, 1);
            bfg[0] = RDB(0, 0, 1); bfg[1] = RDB(0, 1, 1); bfg[2] = RDB(0, 2, 1); bfg[3] = RDB(0, 3, 1);
            BAR(); LGKM0();
            __builtin_amdgcn_s_setprio(1); MFMA16(0); __builtin_amdgcn_s_setprio(0);
            BAR();
        }
        { // ph3
            if (nf) STG_B(0, 2 * it + 2);
            bf16x8 af[4];
            af[0] = RDA(0, 4, 1); af[1] = RDA(0, 5, 1); af[2] = RDA(0, 6, 1); af[3] = RDA(0, 7, 1);
            BAR(); LGKM0();
            __builtin_amdgcn_s_setprio(1); MFMA16(4); __builtin_amdgcn_s_setprio(0);
            if (nf) { asm volatile("s_waitcnt vmcnt(4)" ::: "memory"); }
            else    { asm volatile("s_waitcnt vmcnt(0)" ::: "memory"); }
            BAR();
        }
        { // ph4
            if (nf) STG_A(0, 2 * it + 2);
            bf16x8 af[4];
            af[0] = RDA(1, 0, 0); af[1] = RDA(1, 1, 0); af[2] = RDA(1, 2, 0); af[3] = RDA(1, 3, 0);
            bfg[0] = RDB(1, 0, 0); bfg[1] = RDB(1, 1, 0); bfg[2] = RDB(1, 2, 0); bfg[3] = RDB(1, 3, 0);
            BAR(); LGKM0();
            __builtin_amdgcn_s_setprio(1); MFMA16(0); __builtin_amdgcn_s_setprio(0);
            BAR();
        }
        { // ph5
            bf16x8 af[4];
            af[0] = RDA(1, 4, 0); af[1] = RDA(1, 5, 0); af[2] = RDA(1, 6, 0); af[3] = RDA(1, 7, 0);
            BAR(); LGKM0();
            __builtin_amdgcn_s_setprio(1); MFMA16(4); __builtin_amdgcn_s_setprio(0);
            BAR();
        }
        { // ph6
            bf16x8 af[4];
            af[0] = RDA(1, 0, 1); af[1] = RDA(1, 1, 1); af[2] = RDA(1, 2, 1); af[3] = RDA(1, 3, 1);
            bfg[0] = RDB(1, 0, 1); bfg[1] = RDB(1, 1, 1); bfg[2] = RDB(1, 2, 1); bfg[3] = RDB(1, 3, 1);
            BAR(); LGKM0();
            __builtin_amdgcn_s_setprio(1); MFMA16(0); __builtin_amdgcn_s_setprio(0);
            BAR();
        }
        { // ph7
            if (nf) STG_B(1, 2 * it + 3);
            bf16x8 af[4];
            af[0] = RDA(1, 4, 1); af[1] = RDA(1, 5, 1); af[2] = RDA(1, 6, 1); af[3] = RDA(1, 7, 1);
            BAR(); LGKM0();
            __builtin_amdgcn_s_setprio(1); MFMA16(4); __builtin_amdgcn_s_setprio(0);
            if (nf) { asm volatile("s_waitcnt vmcnt(4)" ::: "memory"); }
            BAR();
        }
    }
#undef STG_A
#undef STG_B
#undef RDA
#undef RDB
#undef MFMA16
#undef LGKM0
#undef BAR

    const int sec = n0 >> 11;
#pragma unroll
    for (int mm = 0; mm < 8; ++mm)
#pragma unroll
        for (int nn = 0; nn < 4; ++nn)
#pragma unroll
            for (int j = 0; j < 4; ++j) {
                int grow = m0 + wm * 128 + mm * 16 + hi * 4 + j;   // b*T + t
                int b = grow >> 11, t = grow & 2047;
                int col = n0 + wn * 64 + nn * 16 + ln;
                int c2 = col & 2047;
                int dd = c2 & 127;
                int h = c2 >> 7;
                size_t bh = (size_t)(b * N_HEADS + h);
                if (sec == 0)      o_q[(bh * T_SEQ + t) * HEAD_D + dd] = f2bf(acc[mm][nn][j]);
                else if (sec == 1) o_k[(bh * T_SEQ + t) * HEAD_D + dd] = f2bf(acc[mm][nn][j]);
                else if (sec == 2) o_vt[(bh * HEAD_D + dd) * T_SEQ + t] = f2bf(acc[mm][nn][j]);
                else {
                    float g = acc[mm][nn][j] + b_gate[c2];
                    g = 1.0f / (1.0f + __expf(-g));
                    o_g[(size_t)grow * D_MODEL + c2] = f2bf(g);
                }
            }
}

// ---------- out GEMM: 128x128, BK=64, dbuf + counted vmcnt(8) (R19 exact) ----------
template <int RGN_M, int RGN_N>
__global__ __launch_bounds__(256) void gemm_bt(
    const ushort_t* __restrict__ A, const ushort_t* __restrict__ Bt,
    int N, int K, float* __restrict__ o_f32)
{
    __shared__ ushort_t As[2][128 * 64];
    __shared__ ushort_t Bs[2][128 * 64];
    const int tid = threadIdx.x;
    const int wid = tid >> 6, l = tid & 63;
    const int ln = l & 15, hi = l >> 4;
    const int lnx = (ln & 7) << 4;
    const int wm = wid >> 1, wn = wid & 1;

    const int lin = blockIdx.x;
    const int r = lin & 7, w = lin >> 3;
    const int bm = (r >> 2) * RGN_M + w / RGN_N;
    const int bn = (r & 3) * RGN_N + w % RGN_N;
    const int m0 = bm * 128, n0 = bn * 128;

    f32x4 acc[4][4];
#pragma unroll
    for (int m = 0; m < 4; ++m)
#pragma unroll
        for (int n = 0; n < 4; ++n) acc[m][n] = (f32x4){0.f, 0.f, 0.f, 0.f};

    const int srow = tid >> 3;
    const int scol = ((tid & 7) ^ (srow & 7)) << 3;
    const ushort_t* Ag = A + (size_t)(m0 + srow) * K + scol;
    const ushort_t* Bg = Bt + (size_t)(n0 + srow) * K + scol;

#define GSTAGE(ktb, Ad, Bd)                                                   \
    {                                                                         \
        _Pragma("unroll")                                                     \
        for (int i_ = 0; i_ < 4; ++i_) {                                      \
            gload16(Ag + (size_t)(i_ * 32) * K + (ktb), (Ad) + i_ * 2048);    \
            gload16(Bg + (size_t)(i_ * 32) * K + (ktb), (Bd) + i_ * 2048);    \
        }                                                                     \
    }

    const int nkt = K >> 6;
    int cur = 0;
    GSTAGE(0, As[0] + wid * 512, Bs[0] + wid * 512);

    for (int t = 0; t < nkt; ++t) {
        if (t + 1 < nkt) {
            GSTAGE((t + 1) << 6, As[cur ^ 1] + wid * 512, Bs[cur ^ 1] + wid * 512);
            asm volatile("s_waitcnt vmcnt(8)" ::: "memory");
        } else {
            asm volatile("s_waitcnt vmcnt(0)" ::: "memory");
        }
        __builtin_amdgcn_s_barrier();

        const char* Ab_ = (const char*)As[cur];
        const char* Bb_ = (const char*)Bs[cur];
        __builtin_amdgcn_s_setprio(1);
#pragma unroll
        for (int kk = 0; kk < 2; ++kk) {
            bf16x8 af[4], bfg[4];
#pragma unroll
            for (int m = 0; m < 4; ++m)
                af[m] = *(const bf16x8*)(Ab_ + (((wm * 64 + m * 16 + ln) << 7) +
                                                (((kk << 6) + (hi << 4)) ^ lnx)));
#pragma unroll
            for (int n = 0; n < 4; ++n)
                bfg[n] = *(const bf16x8*)(Bb_ + (((wn * 64 + n * 16 + ln) << 7) +
                                                 (((kk << 6) + (hi << 4)) ^ lnx)));
#pragma unroll
            for (int m = 0; m < 4; ++m)
#pragma unroll
                for (int n = 0; n < 4; ++n)
                    acc[m][n] = __builtin_amdgcn_mfma_f32_16x16x32_bf16(af[m], bfg[n], acc[m][n], 0, 0, 0);
        }
        __builtin_amdgcn_s_setprio(0);
        asm volatile("s_waitcnt lgkmcnt(0)" ::: "memory");
        __builtin_amdgcn_s_barrier();
        cur ^= 1;
    }
#undef GSTAGE

#pragma unroll
    for (int m = 0; m < 4; ++m)
#pragma unroll
        for (int n = 0; n < 4; ++n)
#pragma unroll
            for (int j = 0; j < 4; ++j) {
                int grow = m0 + wm * 64 + m * 16 + hi * 4 + j;
                int gcol = n0 + wn * 64 + n * 16 + ln;
                o_f32[(size_t)grow * N + gcol] = acc[m][n][j];
            }
}

// ---------- RMSNorm + RoPE, in place on q and k [B,H,T,128] ----------
__global__ __launch_bounds__(256) void rmsrope_kernel(ushort_t* __restrict__ qb, ushort_t* __restrict__ kb) {
    int wid = threadIdx.x >> 6, l = threadIdx.x & 63;
    int row = blockIdx.x * 4 + wid;          // (b*H + h)*T + t
    int t = row & (T_SEQ - 1);
    size_t base = (size_t)row * HEAD_D;

    float ang = (float)t * expf(-(float)l * 0.14391156f);
    float sv, cv;
    sincosf(ang, &sv, &cv);

    float a = bf2f(qb[base + l]), b = bf2f(qb[base + 64 + l]);
    float ss = a * a + b * b;
#pragma unroll
    for (int d = 1; d < 64; d <<= 1) ss += __shfl_xor(ss, d);
    float r = rsqrtf(ss * (1.0f / 128.0f) + 1e-6f);
    a *= r; b *= r;
    qb[base + l]      = f2bf(a * cv - b * sv);
    qb[base + 64 + l] = f2bf(a * sv + b * cv);

    a = bf2f(kb[base + l]); b = bf2f(kb[base + 64 + l]);
    ss = a * a + b * b;
#pragma unroll
    for (int d = 1; d < 64; d <<= 1) ss += __shfl_xor(ss, d);
    r = rsqrtf(ss * (1.0f / 128.0f) + 1e-6f);
    a *= r; b *= r;
    kb[base + l]      = f2bf(a * cv - b * sv);
    kb[base + 64 + l] = f2bf(a * sv + b * cv);
}

// ---------- causal flash attention v7 (R10..R19 passing version, unchanged) ----------
__global__ __launch_bounds__(256) void flash_kernel(
    const ushort_t* __restrict__ qb, const ushort_t* __restrict__ kb,
    const ushort_t* __restrict__ vt, const ushort_t* __restrict__ g_b,
    ushort_t* __restrict__ y_b)
{
    const int bh = blockIdx.x, bxp = blockIdx.y;
    const int tid = threadIdx.x;
    const int wid = tid >> 6, l = tid & 63;
    const int ln = l & 15, hi = l >> 4;
    const int lnx = (ln & 7) << 4;

    const ushort_t* Q  = qb + (size_t)bh * T_SEQ * HEAD_D;
    const ushort_t* Kp = kb + (size_t)bh * T_SEQ * HEAD_D;
    const ushort_t* Vp = vt + (size_t)bh * HEAD_D * T_SEQ;

    __shared__ ushort_t Ks[4][64 * 128];
    __shared__ ushort_t Vs[4][128 * 64];
    __shared__ ushort_t p_all[4][32][72];
    ushort_t (*p_lds)[72] = p_all[wid];

    const float scale_log2 = 0.12752059520313818f;
    const int bb = bh >> 4, h = bh & 15;

    int s_off[4], s_ksrc[4], s_vrow[4], s_vcol[4];
#pragma unroll
    for (int i = 0; i < 4; ++i) {
        int off = (i * 256 + tid) * 16;
        s_off[i] = (i * 4 + wid) * 512;
        int krow = off >> 8;
        s_ksrc[i] = off ^ ((krow & 7) << 4);
        int vrow = off >> 7;
        s_vrow[i] = vrow;
        s_vcol[i] = ((off & 127) ^ ((vrow & 7) << 4)) >> 1;
    }

#define STAGE(kvbase, Kd, Vd)                                                            \
    {                                                                                    \
        _Pragma("unroll")                                                                \
        for (int i_ = 0; i_ < 4; ++i_) {                                                 \
            gload16((const ushort_t*)((const char*)(Kp + (size_t)(kvbase) * HEAD_D) +    \
                                      s_ksrc[i_]), (Kd) + s_off[i_]);                    \
            gload16(Vp + (size_t)s_vrow[i_] * T_SEQ + (kvbase) + s_vcol[i_],             \
                    (Vd) + s_off[i_]);                                                   \
        }                                                                                \
    }

    for (int pass = 0; pass < 2; ++pass) {
        const int qt = pass ? (15 - bxp) : bxp;
        const int q0w = qt * 128 + wid * 32;
        const int nt = 2 * qt + 2;

        bf16x8 qf[2][4];
#pragma unroll
        for (int m = 0; m < 2; ++m)
#pragma unroll
            for (int kk = 0; kk < 4; ++kk)
                qf[m][kk] = *(const bf16x8*)(Q + (size_t)(q0w + m * 16 + ln) * HEAD_D + kk * 32 + hi * 8);

        f32x4 acc_o[2][8];
#pragma unroll
        for (int m = 0; m < 2; ++m)
#pragma unroll
            for (int nd = 0; nd < 8; ++nd) acc_o[m][nd] = (f32x4){0.f, 0.f, 0.f, 0.f};
        float rl[2][4];
#pragma unroll
        for (int m = 0; m < 2; ++m)
#pragma unroll
            for (int j = 0; j < 4; ++j) rl[m][j] = 0.f;

        ushort_t *Ka = Ks[0], *Kb = Ks[1], *Kc = Ks[2], *Kd4 = Ks[3];
        ushort_t *Va = Vs[0], *Vb = Vs[1], *Vc = Vs[2], *Vd4 = Vs[3];

        STAGE(0, Ka, Va);
        STAGE(64, Kb, Vb);

        for (int t = 0; t < nt; ++t) {
            const int kv0 = t * 64;
            if (t + 2 < nt) {
                STAGE(kv0 + 128, Kc, Vc);
                asm volatile("s_waitcnt vmcnt(16)" ::: "memory");
            } else if (t + 1 < nt) {
                asm volatile("s_waitcnt vmcnt(8)" ::: "memory");
            } else {
                asm volatile("s_waitcnt vmcnt(0)" ::: "memory");
            }
            SBAR0();
            __builtin_amdgcn_s_barrier();
            SBAR0();

            if (kv0 <= q0w + 31) {
                const ushort_t* Ksc = Ka;
                const ushort_t* Vsc = Va;

                f32x4 sa[2][4];
#pragma unroll
                for (int m = 0; m < 2; ++m)
#pragma unroll
                    for (int n = 0; n < 4; ++n) sa[m][n] = (f32x4){0.f, 0.f, 0.f, 0.f};
#pragma unroll
                for (int kk = 0; kk < 4; ++kk) {
                    bf16x8 kf[4];
#pragma unroll
                    for (int n = 0; n < 4; ++n)
                        kf[n] = *(const bf16x8*)((const char*)Ksc +
                                 ((((n * 16 + ln) << 8) + (kk << 6) + (hi << 4)) ^ lnx));
#pragma unroll
                    for (int m = 0; m < 2; ++m)
#pragma unroll
                        for (int n = 0; n < 4; ++n)
                            sa[m][n] = __builtin_amdgcn_mfma_f32_16x16x32_bf16(qf[m][kk], kf[n], sa[m][n], 0, 0, 0);
                }

                const bool partial = (kv0 + 63 > q0w);
                if (partial) {
#pragma unroll
                    for (int m = 0; m < 2; ++m)
#pragma unroll
                        for (int n = 0; n < 4; ++n)
#pragma unroll
                            for (int j = 0; j < 4; ++j) {
                                int kv = kv0 + n * 16 + ln;
                                int qrow = q0w + m * 16 + hi * 4 + j;
                                float v = (kv <= qrow) ? sa[m][n][j] * scale_log2 : -1e30f;
                                float p = __builtin_amdgcn_exp2f(v);
                                rl[m][j] += p;
                                p_lds[m * 16 + hi * 4 + j][n * 16 + ln] = f2bf(p);
                            }
                } else {
#pragma unroll
                    for (int m = 0; m < 2; ++m)
#pragma unroll
                        for (int n = 0; n < 4; ++n)
#pragma unroll
                            for (int j = 0; j < 4; ++j) {
                                float p = __builtin_amdgcn_exp2f(sa[m][n][j] * scale_log2);
                                rl[m][j] += p;
                                p_lds[m * 16 + hi * 4 + j][n * 16 + ln] = f2bf(p);
                            }
                }
                asm volatile("s_waitcnt lgkmcnt(0)" ::: "memory");
                SBAR0();

                const bool skipB = (kv0 + 32 > q0w + 31);
                bf16x8 pf[2][2];
#pragma unroll
                for (int m = 0; m < 2; ++m)
#pragma unroll
                    for (int kk2 = 0; kk2 < 2; ++kk2)
                        pf[m][kk2] = *(const bf16x8*)(&p_lds[m * 16 + ln][kk2 * 32 + hi * 8]);
#pragma unroll
                for (int nd = 0; nd < 8; ++nd) {
                    bf16x8 vf = *(const bf16x8*)((const char*)Vsc +
                                 ((((nd * 16 + ln) << 7) + (hi << 4)) ^ lnx));
                    acc_o[0][nd] = __builtin_amdgcn_mfma_f32_16x16x32_bf16(pf[0][0], vf, acc_o[0][nd], 0, 0, 0);
                    acc_o[1][nd] = __builtin_amdgcn_mfma_f32_16x16x32_bf16(pf[1][0], vf, acc_o[1][nd], 0, 0, 0);
                }
                if (!skipB) {
#pragma unroll
                    for (int nd = 0; nd < 8; ++nd) {
                        bf16x8 vf = *(const bf16x8*)((const char*)Vsc +
                                     ((((nd * 16 + ln) << 7) + 64 + (hi << 4)) ^ lnx));
                        acc_o[0][nd] = __builtin_amdgcn_mfma_f32_16x16x32_bf16(pf[0][1], vf, acc_o[0][nd], 0, 0, 0);
                        acc_o[1][nd] = __builtin_amdgcn_mfma_f32_16x16x32_bf16(pf[1][1], vf, acc_o[1][nd], 0, 0, 0);
                    }
                }
            }
            asm volatile("s_waitcnt lgkmcnt(0)" ::: "memory");
            SBAR0();
            __builtin_amdgcn_s_barrier();
            SBAR0();
            ushort_t* tK = Ka; Ka = Kb; Kb = Kc; Kc = Kd4; Kd4 = tK;
            ushort_t* tV = Va; Va = Vb; Vb = Vc; Vc = Vd4; Vd4 = tV;
        }

#pragma unroll
        for (int d = 1; d < 16; d <<= 1)
#pragma unroll
            for (int m = 0; m < 2; ++m)
#pragma unroll
                for (int j = 0; j < 4; ++j)
                    rl[m][j] += __shfl_xor(rl[m][j], d);

#pragma unroll
        for (int m = 0; m < 2; ++m)
#pragma unroll
            for (int j = 0; j < 4; ++j) {
                float inv = 1.0f / rl[m][j];
                int tr = q0w + m * 16 + hi * 4 + j;
#pragma unroll
                for (int nd = 0; nd < 8; ++nd) {
                    size_t idx = ((size_t)(bb * T_SEQ + tr)) * D_MODEL + h * HEAD_D + nd * 16 + ln;
                    y_b[idx] = f2bf(acc_o[m][nd][j] * inv * bf2f(g_b[idx]));
                }
            }
    }
#undef STAGE
}

// ---------- launch ----------
extern "C" void kernel_launch(void* const* d_in, const int* in_sizes, int n_in,
                              void* d_out, int out_size, void* d_ws, size_t ws_size,
                              hipStream_t stream) {
    const float* x      = (const float*)d_in[0];
    const float* W_qkv  = (const float*)d_in[1];
    const float* W_out  = (const float*)d_in[2];
    const float* W_gate = (const float*)d_in[3];
    const float* b_gate = (const float*)d_in[4];
    float* out = (float*)d_out;

    char* ws = (char*)d_ws;
    size_t off = 0;
    ushort_t* xb     = (ushort_t*)(ws + off); off += (size_t)M_ROWS * D_MODEL * 2;
    ushort_t* wqgT   = (ushort_t*)(ws + off); off += (size_t)4 * D_MODEL * D_MODEL * 2;
    ushort_t* woutT  = (ushort_t*)(ws + off); off += (size_t)D_MODEL * D_MODEL * 2;
    ushort_t* q_b    = (ushort_t*)(ws + off); off += (size_t)M_ROWS * D_MODEL * 2;
    ushort_t* k_b    = (ushort_t*)(ws + off); off += (size_t)M_ROWS * D_MODEL * 2;
    ushort_t* v_t    = (ushort_t*)(ws + off); off += (size_t)M_ROWS * D_MODEL * 2;
    ushort_t* g_b    = (ushort_t*)(ws + off); off += (size_t)M_ROWS * D_MODEL * 2;
    ushort_t* y_b    = (ushort_t*)(ws + off); off += (size_t)M_ROWS * D_MODEL * 2;

    prep_kernel<<<8192 + 192 * 64 + 64 * 64 + 64 * 64, 256, 0, stream>>>(
        x, xb, W_qkv, W_gate, W_out, wqgT, woutT);
    gemm256_qkvg<<<512, 512, 0, stream>>>(xb, wqgT, q_b, k_b, v_t, b_gate, g_b);
    rmsrope_kernel<<<16384, 256, 0, stream>>>(q_b, k_b);
    flash_kernel<<<dim3(32, 8), 256, 0, stream>>>(q_b, k_b, v_t, g_b, y_b);
    gemm_bt<16, 4><<<512, 256, 0, stream>>>(y_b, woutT, D_MODEL, D_MODEL, out);
}

// Round 22
// 328.060 us; speedup vs baseline: 1.0872x; 1.0033x over previous
//
#include <hip/hip_runtime.h>
#include <stdint.h>

// ---------- types ----------
typedef unsigned short ushort_t;
typedef __bf16 bf16x8 __attribute__((ext_vector_type(8)));
typedef float f32x4 __attribute__((ext_vector_type(4)));
typedef float float4v __attribute__((ext_vector_type(4)));
typedef unsigned short ushort4v __attribute__((ext_vector_type(4)));

#define T_SEQ 2048
#define D_MODEL 2048
#define N_HEADS 16
#define HEAD_D 128
#define BATCH 2
#define M_ROWS (BATCH * T_SEQ)   // 4096

__device__ __forceinline__ ushort_t f2bf(float f) {
    unsigned u = __builtin_bit_cast(unsigned, f);
    u += 0x7fffu + ((u >> 16) & 1u);   // RNE
    return (ushort_t)(u >> 16);
}
__device__ __forceinline__ float bf2f(ushort_t h) {
    unsigned u = ((unsigned)h) << 16;
    return __builtin_bit_cast(float, u);
}

__device__ __forceinline__ void gload16(const ushort_t* g, ushort_t* l) {
    __builtin_amdgcn_global_load_lds(
        (const __attribute__((address_space(1))) void*)g,
        (__attribute__((address_space(3))) void*)l,
        16, 0, 0);
}

#define SBAR0() __builtin_amdgcn_sched_barrier(0)

// ---------- fused prep (R17 exact) ----------
__global__ __launch_bounds__(256) void prep_kernel(
    const float* __restrict__ x, ushort_t* __restrict__ xb,
    const float* __restrict__ W_qkv, const float* __restrict__ W_gate,
    const float* __restrict__ W_out,
    ushort_t* __restrict__ wqgT, ushort_t* __restrict__ woutT)
{
    const int bid = blockIdx.x;
    if (bid < 8192) {
        int i = bid * 256 + threadIdx.x;
        float4v v = *(const float4v*)(x + (size_t)i * 4);
        ushort4v o;
        o[0] = f2bf(v[0]); o[1] = f2bf(v[1]); o[2] = f2bf(v[2]); o[3] = f2bf(v[3]);
        *(ushort4v*)(xb + (size_t)i * 4) = o;
        return;
    }
    __shared__ float tile[32][33];
    int tix = bid - 8192;
    const float* W; ushort_t* Wt; int Ncols, tnx;
    if (tix < 192 * 64) {
        W = W_qkv; Wt = wqgT; Ncols = 3 * D_MODEL; tnx = tix % 192;
    } else if (tix < 192 * 64 + 64 * 64) {
        tix -= 192 * 64;
        W = W_gate; Wt = wqgT + (size_t)3 * D_MODEL * D_MODEL; Ncols = D_MODEL; tnx = tix % 64;
    } else {
        tix -= 192 * 64 + 64 * 64;
        W = W_out; Wt = woutT; Ncols = D_MODEL; tnx = tix % 64;
    }
    int n0 = tnx * 32, k0 = (tix / ((W == W_qkv) ? 192 : 64)) * 32;
    int tx = threadIdx.x & 31, ty = threadIdx.x >> 5;
#pragma unroll
    for (int i = 0; i < 4; ++i)
        tile[ty + i * 8][tx] = W[(size_t)(k0 + ty + i * 8) * Ncols + n0 + tx];
    __syncthreads();
#pragma unroll
    for (int i = 0; i < 4; ++i)
        Wt[(size_t)(n0 + ty + i * 8) * D_MODEL + k0 + tx] = f2bf(tile[tx][ty + i * 8]);
}

// ---------- QKV+gate GEMM: 256x256, BK=64, 8 waves, 8-phase + fragment read-ahead ----------
// R22: software-pipeline the LDS->reg fragment reads one phase ahead
// (double-buffered aw/bw register sets), so each phase's lgkm(0) waits on
// reads issued ~700cy earlier and the new reads overlap the MFMA cluster.
// Barriers halve: 16 -> 8 per iteration. Parity-boundary prefetches (ph3,ph7)
// issue AFTER the counted vmcnt certification. WAR per stage target verified:
// every staged region's newest reads are lgkm-certified >=1 barrier earlier.
// R18 lesson: launch_bounds(512,2) mandatory (frag-dbuf +64 VGPR, ~220 total).
__global__ __launch_bounds__(512, 2) void gemm256_qkvg(
    const ushort_t* __restrict__ A, const ushort_t* __restrict__ Bt,
    ushort_t* __restrict__ o_q, ushort_t* __restrict__ o_k, ushort_t* __restrict__ o_vt,
    const float* __restrict__ b_gate, ushort_t* __restrict__ o_g)
{
    const int K = D_MODEL;                  // 2048
    __shared__ ushort_t Al[2][16384];       // 64 KB
    __shared__ ushort_t Bl[2][16384];       // 64 KB
    const int tid = threadIdx.x;
    const int l = tid & 63;
    const int ln = l & 15, hi = l >> 4;
    const int lnx = (ln & 7) << 4;
    const int wid = tid >> 6;               // 0..7
    const int wm = wid >> 2, wn = wid & 3;  // 2m x 4n

    const int lin = blockIdx.x;
    const int r = lin & 7, w = lin >> 3;
    const int bm = (r >> 2) * 8 + (w >> 3);
    const int bn = (r & 3) * 8 + (w & 7);
    const int m0 = bm * 256, n0 = bn * 256;

    f32x4 acc[8][4];
#pragma unroll
    for (int mm = 0; mm < 8; ++mm)
#pragma unroll
        for (int nn = 0; nn < 4; ++nn) acc[mm][nn] = (f32x4){0.f, 0.f, 0.f, 0.f};

    const ushort_t* As_0[2]; const ushort_t* As_1[2];
    const ushort_t* Bs_0[2]; const ushort_t* Bs_1[2];
    int dst_[2];
#pragma unroll
    for (int i = 0; i < 2; ++i) {
        int c = i * 512 + tid;
        int row = c >> 3;
        int sc = ((c & 7) ^ (row & 7)) << 3;
        As_0[i] = A + (size_t)(m0 + row) * K + sc;
        As_1[i] = A + (size_t)(m0 + 128 + row) * K + sc;
        Bs_0[i] = Bt + (size_t)(n0 + row) * K + sc;
        Bs_1[i] = Bt + (size_t)(n0 + 128 + row) * K + sc;
        dst_[i] = i * 4096 + wid * 512;
    }

#define STG_A(pq, kt) { _Pragma("unroll") for (int i_ = 0; i_ < 2; ++i_) {     \
        gload16(As_0[i_] + ((kt) << 6), Al[pq] + dst_[i_]);                    \
        gload16(As_1[i_] + ((kt) << 6), Al[pq] + 8192 + dst_[i_]); } }
#define STG_B(pq, kt) { _Pragma("unroll") for (int i_ = 0; i_ < 2; ++i_) {     \
        gload16(Bs_0[i_] + ((kt) << 6), Bl[pq] + dst_[i_]);                    \
        gload16(Bs_1[i_] + ((kt) << 6), Bl[pq] + 8192 + dst_[i_]); } }

#define RDA(P, mm_, kk_) (*(const bf16x8*)((const char*)Al[P] + (wm << 14) +   \
        ((((mm_) << 4) + ln) << 7) + ((((kk_) << 6) + (hi << 4)) ^ lnx)))
#define RDB(P, nn_, kk_) (*(const bf16x8*)((const char*)Bl[P] + ((wn >> 1) << 14) + \
        ((((wn & 1) << 6) + ((nn_) << 4) + ln) << 7) + ((((kk_) << 6) + (hi << 4)) ^ lnx)))

#define LDA4(D_, P, MB, kk_) { D_[0] = RDA(P, (MB), kk_); D_[1] = RDA(P, (MB)+1, kk_); \
        D_[2] = RDA(P, (MB)+2, kk_); D_[3] = RDA(P, (MB)+3, kk_); }
#define LDB4(D_, P, kk_) { D_[0] = RDB(P, 0, kk_); D_[1] = RDB(P, 1, kk_); \
        D_[2] = RDB(P, 2, kk_); D_[3] = RDB(P, 3, kk_); }

#define MFMA16F(MLO, A_, B_) { _Pragma("unroll") for (int mm = 0; mm < 4; ++mm) \
        _Pragma("unroll") for (int nn = 0; nn < 4; ++nn)                        \
        acc[(MLO) + mm][nn] = __builtin_amdgcn_mfma_f32_16x16x32_bf16(          \
            A_[mm], B_[nn], acc[(MLO) + mm][nn], 0, 0, 0); }

// rule #18: pin MFMA below the lgkm wait
#define LGKM0() { asm volatile("s_waitcnt lgkmcnt(0)" ::: "memory"); SBAR0(); }
#define BAR() __builtin_amdgcn_s_barrier()

    // prologue: tiles 0,1 staged; tile 0 certified; ph0 fragments prefetched
    STG_A(0, 0); STG_B(0, 0);
    STG_A(1, 1); STG_B(1, 1);
    asm volatile("s_waitcnt vmcnt(8)" ::: "memory");
    BAR();
    bf16x8 aw0[4], aw1[4], bw0[4], bw1[4];
    LDA4(aw0, 0, 0, 0);
    LDB4(bw0, 0, 0);

    const int NIT = K >> 7;                 // 16 iterations x 2 K-tiles
    for (int it = 0; it < NIT; ++it) {
        const bool nf = (it + 1 < NIT);
        { // ph0: compute (aw0,bw0); stage A->p1; prefetch ph1 A
            LGKM0();
            if (it > 0) STG_A(1, 2 * it + 1);
            LDA4(aw1, 0, 4, 0);
            __builtin_amdgcn_s_setprio(1); MFMA16F(0, aw0, bw0); __builtin_amdgcn_s_setprio(0);
            BAR();
        }
        { // ph1: compute (aw1,bw0); prefetch ph2 A+B (kk1)
            LGKM0();
            LDA4(aw0, 0, 0, 1);
            LDB4(bw1, 0, 1);
            __builtin_amdgcn_s_setprio(1); MFMA16F(4, aw1, bw0); __builtin_amdgcn_s_setprio(0);
            BAR();
        }
        { // ph2: compute (aw0,bw1); prefetch ph3 A
            LGKM0();
            LDA4(aw1, 0, 4, 1);
            __builtin_amdgcn_s_setprio(1); MFMA16F(0, aw0, bw1); __builtin_amdgcn_s_setprio(0);
            BAR();
        }
        { // ph3: compute (aw1,bw1); stage B->p0; certify parity 1; prefetch ph4 (p1)
            LGKM0();
            if (nf) STG_B(0, 2 * it + 2);
            __builtin_amdgcn_s_setprio(1); MFMA16F(4, aw1, bw1); __builtin_amdgcn_s_setprio(0);
            if (nf) { asm volatile("s_waitcnt vmcnt(4)" ::: "memory"); }
            else    { asm volatile("s_waitcnt vmcnt(0)" ::: "memory"); }
            LDA4(aw0, 1, 0, 0);
            LDB4(bw0, 1, 0);
            BAR();
        }
        { // ph4: compute (aw0,bw0); stage A->p0; prefetch ph5 A
            LGKM0();
            if (nf) STG_A(0, 2 * it + 2);
            LDA4(aw1, 1, 4, 0);
            __builtin_amdgcn_s_setprio(1); MFMA16F(0, aw0, bw0); __builtin_amdgcn_s_setprio(0);
            BAR();
        }
        { // ph5: compute (aw1,bw0); prefetch ph6 A+B (kk1)
            LGKM0();
            LDA4(aw0, 1, 0, 1);
            LDB4(bw1, 1, 1);
            __builtin_amdgcn_s_setprio(1); MFMA16F(4, aw1, bw0); __builtin_amdgcn_s_setprio(0);
            BAR();
        }
        { // ph6: compute (aw0,bw1); prefetch ph7 A
            LGKM0();
            LDA4(aw1, 1, 4, 1);
            __builtin_amdgcn_s_setprio(1); MFMA16F(0, aw0, bw1); __builtin_amdgcn_s_setprio(0);
            BAR();
        }
        { // ph7: compute (aw1,bw1); stage B->p1; certify parity 0; prefetch next ph0 (p0)
            LGKM0();
            if (nf) STG_B(1, 2 * it + 3);
            __builtin_amdgcn_s_setprio(1); MFMA16F(4, aw1, bw1); __builtin_amdgcn_s_setprio(0);
            if (nf) {
                asm volatile("s_waitcnt vmcnt(4)" ::: "memory");
                LDA4(aw0, 0, 0, 0);
                LDB4(bw0, 0, 0);
            }
            BAR();
        }
    }
#undef STG_A
#undef STG_B
#undef RDA
#undef RDB
#undef LDA4
#undef LDB4
#undef MFMA16F
#undef LGKM0
#undef BAR

    const int sec = n0 >> 11;
#pragma unroll
    for (int mm = 0; mm < 8; ++mm)
#pragma unroll
        for (int nn = 0; nn < 4; ++nn)
#pragma unroll
            for (int j = 0; j < 4; ++j) {
                int grow = m0 + wm * 128 + mm * 16 + hi * 4 + j;   // b*T + t
                int b = grow >> 11, t = grow & 2047;
                int col = n0 + wn * 64 + nn * 16 + ln;
                int c2 = col & 2047;
                int dd = c2 & 127;
                int h = c2 >> 7;
                size_t bh = (size_t)(b * N_HEADS + h);
                if (sec == 0)      o_q[(bh * T_SEQ + t) * HEAD_D + dd] = f2bf(acc[mm][nn][j]);
                else if (sec == 1) o_k[(bh * T_SEQ + t) * HEAD_D + dd] = f2bf(acc[mm][nn][j]);
                else if (sec == 2) o_vt[(bh * HEAD_D + dd) * T_SEQ + t] = f2bf(acc[mm][nn][j]);
                else {
                    float g = acc[mm][nn][j] + b_gate[c2];
                    g = 1.0f / (1.0f + __expf(-g));
                    o_g[(size_t)grow * D_MODEL + c2] = f2bf(g);
                }
            }
}

// ---------- out GEMM: 128x128, BK=64, dbuf + counted vmcnt(8) (R19/R21 exact) ----------
template <int RGN_M, int RGN_N>
__global__ __launch_bounds__(256) void gemm_bt(
    const ushort_t* __restrict__ A, const ushort_t* __restrict__ Bt,
    int N, int K, float* __restrict__ o_f32)
{
    __shared__ ushort_t As[2][128 * 64];
    __shared__ ushort_t Bs[2][128 * 64];
    const int tid = threadIdx.x;
    const int wid = tid >> 6, l = tid & 63;
    const int ln = l & 15, hi = l >> 4;
    const int lnx = (ln & 7) << 4;
    const int wm = wid >> 1, wn = wid & 1;

    const int lin = blockIdx.x;
    const int r = lin & 7, w = lin >> 3;
    const int bm = (r >> 2) * RGN_M + w / RGN_N;
    const int bn = (r & 3) * RGN_N + w % RGN_N;
    const int m0 = bm * 128, n0 = bn * 128;

    f32x4 acc[4][4];
#pragma unroll
    for (int m = 0; m < 4; ++m)
#pragma unroll
        for (int n = 0; n < 4; ++n) acc[m][n] = (f32x4){0.f, 0.f, 0.f, 0.f};

    const int srow = tid >> 3;
    const int scol = ((tid & 7) ^ (srow & 7)) << 3;
    const ushort_t* Ag = A + (size_t)(m0 + srow) * K + scol;
    const ushort_t* Bg = Bt + (size_t)(n0 + srow) * K + scol;

#define GSTAGE(ktb, Ad, Bd)                                                   \
    {                                                                         \
        _Pragma("unroll")                                                     \
        for (int i_ = 0; i_ < 4; ++i_) {                                      \
            gload16(Ag + (size_t)(i_ * 32) * K + (ktb), (Ad) + i_ * 2048);    \
            gload16(Bg + (size_t)(i_ * 32) * K + (ktb), (Bd) + i_ * 2048);    \
        }                                                                     \
    }

    const int nkt = K >> 6;
    int cur = 0;
    GSTAGE(0, As[0] + wid * 512, Bs[0] + wid * 512);

    for (int t = 0; t < nkt; ++t) {
        if (t + 1 < nkt) {
            GSTAGE((t + 1) << 6, As[cur ^ 1] + wid * 512, Bs[cur ^ 1] + wid * 512);
            asm volatile("s_waitcnt vmcnt(8)" ::: "memory");
        } else {
            asm volatile("s_waitcnt vmcnt(0)" ::: "memory");
        }
        __builtin_amdgcn_s_barrier();

        const char* Ab_ = (const char*)As[cur];
        const char* Bb_ = (const char*)Bs[cur];
        __builtin_amdgcn_s_setprio(1);
#pragma unroll
        for (int kk = 0; kk < 2; ++kk) {
            bf16x8 af[4], bfg[4];
#pragma unroll
            for (int m = 0; m < 4; ++m)
                af[m] = *(const bf16x8*)(Ab_ + (((wm * 64 + m * 16 + ln) << 7) +
                                                (((kk << 6) + (hi << 4)) ^ lnx)));
#pragma unroll
            for (int n = 0; n < 4; ++n)
                bfg[n] = *(const bf16x8*)(Bb_ + (((wn * 64 + n * 16 + ln) << 7) +
                                                 (((kk << 6) + (hi << 4)) ^ lnx)));
#pragma unroll
            for (int m = 0; m < 4; ++m)
#pragma unroll
                for (int n = 0; n < 4; ++n)
                    acc[m][n] = __builtin_amdgcn_mfma_f32_16x16x32_bf16(af[m], bfg[n], acc[m][n], 0, 0, 0);
        }
        __builtin_amdgcn_s_setprio(0);
        asm volatile("s_waitcnt lgkmcnt(0)" ::: "memory");
        __builtin_amdgcn_s_barrier();
        cur ^= 1;
    }
#undef GSTAGE

#pragma unroll
    for (int m = 0; m < 4; ++m)
#pragma unroll
        for (int n = 0; n < 4; ++n)
#pragma unroll
            for (int j = 0; j < 4; ++j) {
                int grow = m0 + wm * 64 + m * 16 + hi * 4 + j;
                int gcol = n0 + wn * 64 + n * 16 + ln;
                o_f32[(size_t)grow * N + gcol] = acc[m][n][j];
            }
}

// ---------- RMSNorm + RoPE, in place on q and k [B,H,T,128] ----------
__global__ __launch_bounds__(256) void rmsrope_kernel(ushort_t* __restrict__ qb, ushort_t* __restrict__ kb) {
    int wid = threadIdx.x >> 6, l = threadIdx.x & 63;
    int row = blockIdx.x * 4 + wid;          // (b*H + h)*T + t
    int t = row & (T_SEQ - 1);
    size_t base = (size_t)row * HEAD_D;

    float ang = (float)t * expf(-(float)l * 0.14391156f);
    float sv, cv;
    sincosf(ang, &sv, &cv);

    float a = bf2f(qb[base + l]), b = bf2f(qb[base + 64 + l]);
    float ss = a * a + b * b;
#pragma unroll
    for (int d = 1; d < 64; d <<= 1) ss += __shfl_xor(ss, d);
    float r = rsqrtf(ss * (1.0f / 128.0f) + 1e-6f);
    a *= r; b *= r;
    qb[base + l]      = f2bf(a * cv - b * sv);
    qb[base + 64 + l] = f2bf(a * sv + b * cv);

    a = bf2f(kb[base + l]); b = bf2f(kb[base + 64 + l]);
    ss = a * a + b * b;
#pragma unroll
    for (int d = 1; d < 64; d <<= 1) ss += __shfl_xor(ss, d);
    r = rsqrtf(ss * (1.0f / 128.0f) + 1e-6f);
    a *= r; b *= r;
    kb[base + l]      = f2bf(a * cv - b * sv);
    kb[base + 64 + l] = f2bf(a * sv + b * cv);
}

// ---------- causal flash attention v7 (R10..R21 passing version, unchanged) ----------
__global__ __launch_bounds__(256) void flash_kernel(
    const ushort_t* __restrict__ qb, const ushort_t* __restrict__ kb,
    const ushort_t* __restrict__ vt, const ushort_t* __restrict__ g_b,
    ushort_t* __restrict__ y_b)
{
    const int bh = blockIdx.x, bxp = blockIdx.y;
    const int tid = threadIdx.x;
    const int wid = tid >> 6, l = tid & 63;
    const int ln = l & 15, hi = l >> 4;
    const int lnx = (ln & 7) << 4;

    const ushort_t* Q  = qb + (size_t)bh * T_SEQ * HEAD_D;
    const ushort_t* Kp = kb + (size_t)bh * T_SEQ * HEAD_D;
    const ushort_t* Vp = vt + (size_t)bh * HEAD_D * T_SEQ;

    __shared__ ushort_t Ks[4][64 * 128];
    __shared__ ushort_t Vs[4][128 * 64];
    __shared__ ushort_t p_all[4][32][72];
    ushort_t (*p_lds)[72] = p_all[wid];

    const float scale_log2 = 0.12752059520313818f;
    const int bb = bh >> 4, h = bh & 15;

    int s_off[4], s_ksrc[4], s_vrow[4], s_vcol[4];
#pragma unroll
    for (int i = 0; i < 4; ++i) {
        int off = (i * 256 + tid) * 16;
        s_off[i] = (i * 4 + wid) * 512;
        int krow = off >> 8;
        s_ksrc[i] = off ^ ((krow & 7) << 4);
        int vrow = off >> 7;
        s_vrow[i] = vrow;
        s_vcol[i] = ((off & 127) ^ ((vrow & 7) << 4)) >> 1;
    }

#define STAGE(kvbase, Kd, Vd)                                                            \
    {                                                                                    \
        _Pragma("unroll")                                                                \
        for (int i_ = 0; i_ < 4; ++i_) {                                                 \
            gload16((const ushort_t*)((const char*)(Kp + (size_t)(kvbase) * HEAD_D) +    \
                                      s_ksrc[i_]), (Kd) + s_off[i_]);                    \
            gload16(Vp + (size_t)s_vrow[i_] * T_SEQ + (kvbase) + s_vcol[i_],             \
                    (Vd) + s_off[i_]);                                                   \
        }                                                                                \
    }

    for (int pass = 0; pass < 2; ++pass) {
        const int qt = pass ? (15 - bxp) : bxp;
        const int q0w = qt * 128 + wid * 32;
        const int nt = 2 * qt + 2;

        bf16x8 qf[2][4];
#pragma unroll
        for (int m = 0; m < 2; ++m)
#pragma unroll
            for (int kk = 0; kk < 4; ++kk)
                qf[m][kk] = *(const bf16x8*)(Q + (size_t)(q0w + m * 16 + ln) * HEAD_D + kk * 32 + hi * 8);

        f32x4 acc_o[2][8];
#pragma unroll
        for (int m = 0; m < 2; ++m)
#pragma unroll
            for (int nd = 0; nd < 8; ++nd) acc_o[m][nd] = (f32x4){0.f, 0.f, 0.f, 0.f};
        float rl[2][4];
#pragma unroll
        for (int m = 0; m < 2; ++m)
#pragma unroll
            for (int j = 0; j < 4; ++j) rl[m][j] = 0.f;

        ushort_t *Ka = Ks[0], *Kb = Ks[1], *Kc = Ks[2], *Kd4 = Ks[3];
        ushort_t *Va = Vs[0], *Vb = Vs[1], *Vc = Vs[2], *Vd4 = Vs[3];

        STAGE(0, Ka, Va);
        STAGE(64, Kb, Vb);

        for (int t = 0; t < nt; ++t) {
            const int kv0 = t * 64;
            if (t + 2 < nt) {
                STAGE(kv0 + 128, Kc, Vc);
                asm volatile("s_waitcnt vmcnt(16)" ::: "memory");
            } else if (t + 1 < nt) {
                asm volatile("s_waitcnt vmcnt(8)" ::: "memory");
            } else {
                asm volatile("s_waitcnt vmcnt(0)" ::: "memory");
            }
            SBAR0();
            __builtin_amdgcn_s_barrier();
            SBAR0();

            if (kv0 <= q0w + 31) {
                const ushort_t* Ksc = Ka;
                const ushort_t* Vsc = Va;

                f32x4 sa[2][4];
#pragma unroll
                for (int m = 0; m < 2; ++m)
#pragma unroll
                    for (int n = 0; n < 4; ++n) sa[m][n] = (f32x4){0.f, 0.f, 0.f, 0.f};
#pragma unroll
                for (int kk = 0; kk < 4; ++kk) {
                    bf16x8 kf[4];
#pragma unroll
                    for (int n = 0; n < 4; ++n)
                        kf[n] = *(const bf16x8*)((const char*)Ksc +
                                 ((((n * 16 + ln) << 8) + (kk << 6) + (hi << 4)) ^ lnx));
#pragma unroll
                    for (int m = 0; m < 2; ++m)
#pragma unroll
                        for (int n = 0; n < 4; ++n)
                            sa[m][n] = __builtin_amdgcn_mfma_f32_16x16x32_bf16(qf[m][kk], kf[n], sa[m][n], 0, 0, 0);
                }

                const bool partial = (kv0 + 63 > q0w);
                if (partial) {
#pragma unroll
                    for (int m = 0; m < 2; ++m)
#pragma unroll
                        for (int n = 0; n < 4; ++n)
#pragma unroll
                            for (int j = 0; j < 4; ++j) {
                                int kv = kv0 + n * 16 + ln;
                                int qrow = q0w + m * 16 + hi * 4 + j;
                                float v = (kv <= qrow) ? sa[m][n][j] * scale_log2 : -1e30f;
                                float p = __builtin_amdgcn_exp2f(v);
                                rl[m][j] += p;
                                p_lds[m * 16 + hi * 4 + j][n * 16 + ln] = f2bf(p);
                            }
                } else {
#pragma unroll
                    for (int m = 0; m < 2; ++m)
#pragma unroll
                        for (int n = 0; n < 4; ++n)
#pragma unroll
                            for (int j = 0; j < 4; ++j) {
                                float p = __builtin_amdgcn_exp2f(sa[m][n][j] * scale_log2);
                                rl[m][j] += p;
                                p_lds[m * 16 + hi * 4 + j][n * 16 + ln] = f2bf(p);
                            }
                }
                asm volatile("s_waitcnt lgkmcnt(0)" ::: "memory");
                SBAR0();

                const bool skipB = (kv0 + 32 > q0w + 31);
                bf16x8 pf[2][2];
#pragma unroll
                for (int m = 0; m < 2; ++m)
#pragma unroll
                    for (int kk2 = 0; kk2 < 2; ++kk2)
                        pf[m][kk2] = *(const bf16x8*)(&p_lds[m * 16 + ln][kk2 * 32 + hi * 8]);
#pragma unroll
                for (int nd = 0; nd < 8; ++nd) {
                    bf16x8 vf = *(const bf16x8*)((const char*)Vsc +
                                 ((((nd * 16 + ln) << 7) + (hi << 4)) ^ lnx));
                    acc_o[0][nd] = __builtin_amdgcn_mfma_f32_16x16x32_bf16(pf[0][0], vf, acc_o[0][nd], 0, 0, 0);
                    acc_o[1][nd] = __builtin_amdgcn_mfma_f32_16x16x32_bf16(pf[1][0], vf, acc_o[1][nd], 0, 0, 0);
                }
                if (!skipB) {
#pragma unroll
                    for (int nd = 0; nd < 8; ++nd) {
                        bf16x8 vf = *(const bf16x8*)((const char*)Vsc +
                                     ((((nd * 16 + ln) << 7) + 64 + (hi << 4)) ^ lnx));
                        acc_o[0][nd] = __builtin_amdgcn_mfma_f32_16x16x32_bf16(pf[0][1], vf, acc_o[0][nd], 0, 0, 0);
                        acc_o[1][nd] = __builtin_amdgcn_mfma_f32_16x16x32_bf16(pf[1][1], vf, acc_o[1][nd], 0, 0, 0);
                    }
                }
            }
            asm volatile("s_waitcnt lgkmcnt(0)" ::: "memory");
            SBAR0();
            __builtin_amdgcn_s_barrier();
            SBAR0();
            ushort_t* tK = Ka; Ka = Kb; Kb = Kc; Kc = Kd4; Kd4 = tK;
            ushort_t* tV = Va; Va = Vb; Vb = Vc; Vc = Vd4; Vd4 = tV;
        }

#pragma unroll
        for (int d = 1; d < 16; d <<= 1)
#pragma unroll
            for (int m = 0; m < 2; ++m)
#pragma unroll
                for (int j = 0; j < 4; ++j)
                    rl[m][j] += __shfl_xor(rl[m][j], d);

#pragma unroll
        for (int m = 0; m < 2; ++m)
#pragma unroll
            for (int j = 0; j < 4; ++j) {
                float inv = 1.0f / rl[m][j];
                int tr = q0w + m * 16 + hi * 4 + j;
#pragma unroll
                for (int nd = 0; nd < 8; ++nd) {
                    size_t idx = ((size_t)(bb * T_SEQ + tr)) * D_MODEL + h * HEAD_D + nd * 16 + ln;
                    y_b[idx] = f2bf(acc_o[m][nd][j] * inv * bf2f(g_b[idx]));
                }
            }
    }
#undef STAGE
}

// ---------- launch ----------
extern "C" void kernel_launch(void* const* d_in, const int* in_sizes, int n_in,
                              void* d_out, int out_size, void* d_ws, size_t ws_size,
                              hipStream_t stream) {
    const float* x      = (const float*)d_in[0];
    const float* W_qkv  = (const float*)d_in[1];
    const float* W_out  = (const float*)d_in[2];
    const float* W_gate = (const float*)d_in[3];
    const float* b_gate = (const float*)d_in[4];
    float* out = (float*)d_out;

    char* ws = (char*)d_ws;
    size_t off = 0;
    ushort_t* xb     = (ushort_t*)(ws + off); off += (size_t)M_ROWS * D_MODEL * 2;
    ushort_t* wqgT   = (ushort_t*)(ws + off); off += (size_t)4 * D_MODEL * D_MODEL * 2;
    ushort_t* woutT  = (ushort_t*)(ws + off); off += (size_t)D_MODEL * D_MODEL * 2;
    ushort_t* q_b    = (ushort_t*)(ws + off); off += (size_t)M_ROWS * D_MODEL * 2;
    ushort_t* k_b    = (ushort_t*)(ws + off); off += (size_t)M_ROWS * D_MODEL * 2;
    ushort_t* v_t    = (ushort_t*)(ws + off); off += (size_t)M_ROWS * D_MODEL * 2;
    ushort_t* g_b    = (ushort_t*)(ws + off); off += (size_t)M_ROWS * D_MODEL * 2;
    ushort_t* y_b    = (ushort_t*)(ws + off); off += (size_t)M_ROWS * D_MODEL * 2;

    prep_kernel<<<8192 + 192 * 64 + 64 * 64 + 64 * 64, 256, 0, stream>>>(
        x, xb, W_qkv, W_gate, W_out, wqgT, woutT);
    gemm256_qkvg<<<512, 512, 0, stream>>>(xb, wqgT, q_b, k_b, v_t, b_gate, g_b);
    rmsrope_kernel<<<16384, 256, 0, stream>>>(q_b, k_b);
    flash_kernel<<<dim3(32, 8), 256, 0, stream>>>(q_b, k_b, v_t, g_b, y_b);
    gemm_bt<16, 4><<<512, 256, 0, stream>>>(y_b, woutT, D_MODEL, D_MODEL, out);
}

// Round 23
// 327.835 us; speedup vs baseline: 1.0879x; 1.0007x over previous
//
#include <hip/hip_runtime.h>
#include <stdint.h>

// ---------- types ----------
typedef unsigned short ushort_t;
typedef __bf16 bf16x8 __attribute__((ext_vector_type(8)));
typedef float f32x4 __attribute__((ext_vector_type(4)));
typedef float float4v __attribute__((ext_vector_type(4)));
typedef unsigned short ushort4v __attribute__((ext_vector_type(4)));

#define T_SEQ 2048
#define D_MODEL 2048
#define N_HEADS 16
#define HEAD_D 128
#define BATCH 2
#define M_ROWS (BATCH * T_SEQ)   // 4096

__device__ __forceinline__ ushort_t f2bf(float f) {
    unsigned u = __builtin_bit_cast(unsigned, f);
    u += 0x7fffu + ((u >> 16) & 1u);   // RNE
    return (ushort_t)(u >> 16);
}
__device__ __forceinline__ float bf2f(ushort_t h) {
    unsigned u = ((unsigned)h) << 16;
    return __builtin_bit_cast(float, u);
}

__device__ __forceinline__ void gload16(const ushort_t* g, ushort_t* l) {
    __builtin_amdgcn_global_load_lds(
        (const __attribute__((address_space(1))) void*)g,
        (__attribute__((address_space(3))) void*)l,
        16, 0, 0);
}

#define SBAR0() __builtin_amdgcn_sched_barrier(0)

// ---------- fused prep (R17 exact) ----------
__global__ __launch_bounds__(256) void prep_kernel(
    const float* __restrict__ x, ushort_t* __restrict__ xb,
    const float* __restrict__ W_qkv, const float* __restrict__ W_gate,
    const float* __restrict__ W_out,
    ushort_t* __restrict__ wqgT, ushort_t* __restrict__ woutT)
{
    const int bid = blockIdx.x;
    if (bid < 8192) {
        int i = bid * 256 + threadIdx.x;
        float4v v = *(const float4v*)(x + (size_t)i * 4);
        ushort4v o;
        o[0] = f2bf(v[0]); o[1] = f2bf(v[1]); o[2] = f2bf(v[2]); o[3] = f2bf(v[3]);
        *(ushort4v*)(xb + (size_t)i * 4) = o;
        return;
    }
    __shared__ float tile[32][33];
    int tix = bid - 8192;
    const float* W; ushort_t* Wt; int Ncols, tnx;
    if (tix < 192 * 64) {
        W = W_qkv; Wt = wqgT; Ncols = 3 * D_MODEL; tnx = tix % 192;
    } else if (tix < 192 * 64 + 64 * 64) {
        tix -= 192 * 64;
        W = W_gate; Wt = wqgT + (size_t)3 * D_MODEL * D_MODEL; Ncols = D_MODEL; tnx = tix % 64;
    } else {
        tix -= 192 * 64 + 64 * 64;
        W = W_out; Wt = woutT; Ncols = D_MODEL; tnx = tix % 64;
    }
    int n0 = tnx * 32, k0 = (tix / ((W == W_qkv) ? 192 : 64)) * 32;
    int tx = threadIdx.x & 31, ty = threadIdx.x >> 5;
#pragma unroll
    for (int i = 0; i < 4; ++i)
        tile[ty + i * 8][tx] = W[(size_t)(k0 + ty + i * 8) * Ncols + n0 + tx];
    __syncthreads();
#pragma unroll
    for (int i = 0; i < 4; ++i)
        Wt[(size_t)(n0 + ty + i * 8) * D_MODEL + k0 + tx] = f2bf(tile[tx][ty + i * 8]);
}

// ---------- QKV+gate GEMM: 256x256, BK=64, 8 waves, 8-phase + fragment read-ahead ----------
// R22/R23 final: software-pipelined LDS->reg fragment reads one phase ahead
// (double-buffered aw/bw register sets); each phase's lgkm(0) waits on reads
// issued ~700cy earlier; new reads overlap the MFMA cluster. 8 barriers/iter.
// Parity-boundary prefetches (ph3,ph7) issue AFTER the counted vmcnt.
// launch_bounds(512,2) mandatory (R18: 4 waves/SIMD spills accumulators).
// Session best: 184.5 µs (744 TF, MfmaUtil 30.8%, 0 bank conflicts, no spill).
__global__ __launch_bounds__(512, 2) void gemm256_qkvg(
    const ushort_t* __restrict__ A, const ushort_t* __restrict__ Bt,
    ushort_t* __restrict__ o_q, ushort_t* __restrict__ o_k, ushort_t* __restrict__ o_vt,
    const float* __restrict__ b_gate, ushort_t* __restrict__ o_g)
{
    const int K = D_MODEL;                  // 2048
    __shared__ ushort_t Al[2][16384];       // 64 KB
    __shared__ ushort_t Bl[2][16384];       // 64 KB
    const int tid = threadIdx.x;
    const int l = tid & 63;
    const int ln = l & 15, hi = l >> 4;
    const int lnx = (ln & 7) << 4;
    const int wid = tid >> 6;               // 0..7
    const int wm = wid >> 2, wn = wid & 3;  // 2m x 4n

    const int lin = blockIdx.x;
    const int r = lin & 7, w = lin >> 3;
    const int bm = (r >> 2) * 8 + (w >> 3);
    const int bn = (r & 3) * 8 + (w & 7);
    const int m0 = bm * 256, n0 = bn * 256;

    f32x4 acc[8][4];
#pragma unroll
    for (int mm = 0; mm < 8; ++mm)
#pragma unroll
        for (int nn = 0; nn < 4; ++nn) acc[mm][nn] = (f32x4){0.f, 0.f, 0.f, 0.f};

    const ushort_t* As_0[2]; const ushort_t* As_1[2];
    const ushort_t* Bs_0[2]; const ushort_t* Bs_1[2];
    int dst_[2];
#pragma unroll
    for (int i = 0; i < 2; ++i) {
        int c = i * 512 + tid;
        int row = c >> 3;
        int sc = ((c & 7) ^ (row & 7)) << 3;
        As_0[i] = A + (size_t)(m0 + row) * K + sc;
        As_1[i] = A + (size_t)(m0 + 128 + row) * K + sc;
        Bs_0[i] = Bt + (size_t)(n0 + row) * K + sc;
        Bs_1[i] = Bt + (size_t)(n0 + 128 + row) * K + sc;
        dst_[i] = i * 4096 + wid * 512;
    }

#define STG_A(pq, kt) { _Pragma("unroll") for (int i_ = 0; i_ < 2; ++i_) {     \
        gload16(As_0[i_] + ((kt) << 6), Al[pq] + dst_[i_]);                    \
        gload16(As_1[i_] + ((kt) << 6), Al[pq] + 8192 + dst_[i_]); } }
#define STG_B(pq, kt) { _Pragma("unroll") for (int i_ = 0; i_ < 2; ++i_) {     \
        gload16(Bs_0[i_] + ((kt) << 6), Bl[pq] + dst_[i_]);                    \
        gload16(Bs_1[i_] + ((kt) << 6), Bl[pq] + 8192 + dst_[i_]); } }

#define RDA(P, mm_, kk_) (*(const bf16x8*)((const char*)Al[P] + (wm << 14) +   \
        ((((mm_) << 4) + ln) << 7) + ((((kk_) << 6) + (hi << 4)) ^ lnx)))
#define RDB(P, nn_, kk_) (*(const bf16x8*)((const char*)Bl[P] + ((wn >> 1) << 14) + \
        ((((wn & 1) << 6) + ((nn_) << 4) + ln) << 7) + ((((kk_) << 6) + (hi << 4)) ^ lnx)))

#define LDA4(D_, P, MB, kk_) { D_[0] = RDA(P, (MB), kk_); D_[1] = RDA(P, (MB)+1, kk_); \
        D_[2] = RDA(P, (MB)+2, kk_); D_[3] = RDA(P, (MB)+3, kk_); }
#define LDB4(D_, P, kk_) { D_[0] = RDB(P, 0, kk_); D_[1] = RDB(P, 1, kk_); \
        D_[2] = RDB(P, 2, kk_); D_[3] = RDB(P, 3, kk_); }

#define MFMA16F(MLO, A_, B_) { _Pragma("unroll") for (int mm = 0; mm < 4; ++mm) \
        _Pragma("unroll") for (int nn = 0; nn < 4; ++nn)                        \
        acc[(MLO) + mm][nn] = __builtin_amdgcn_mfma_f32_16x16x32_bf16(          \
            A_[mm], B_[nn], acc[(MLO) + mm][nn], 0, 0, 0); }

// rule #18: pin MFMA below the lgkm wait
#define LGKM0() { asm volatile("s_waitcnt lgkmcnt(0)" ::: "memory"); SBAR0(); }
#define BAR() __builtin_amdgcn_s_barrier()

    // prologue: tiles 0,1 staged; tile 0 certified; ph0 fragments prefetched
    STG_A(0, 0); STG_B(0, 0);
    STG_A(1, 1); STG_B(1, 1);
    asm volatile("s_waitcnt vmcnt(8)" ::: "memory");
    BAR();
    bf16x8 aw0[4], aw1[4], bw0[4], bw1[4];
    LDA4(aw0, 0, 0, 0);
    LDB4(bw0, 0, 0);

    const int NIT = K >> 7;                 // 16 iterations x 2 K-tiles
    for (int it = 0; it < NIT; ++it) {
        const bool nf = (it + 1 < NIT);
        { // ph0: compute (aw0,bw0); stage A->p1; prefetch ph1 A
            LGKM0();
            if (it > 0) STG_A(1, 2 * it + 1);
            LDA4(aw1, 0, 4, 0);
            __builtin_amdgcn_s_setprio(1); MFMA16F(0, aw0, bw0); __builtin_amdgcn_s_setprio(0);
            BAR();
        }
        { // ph1: compute (aw1,bw0); prefetch ph2 A+B (kk1)
            LGKM0();
            LDA4(aw0, 0, 0, 1);
            LDB4(bw1, 0, 1);
            __builtin_amdgcn_s_setprio(1); MFMA16F(4, aw1, bw0); __builtin_amdgcn_s_setprio(0);
            BAR();
        }
        { // ph2: compute (aw0,bw1); prefetch ph3 A
            LGKM0();
            LDA4(aw1, 0, 4, 1);
            __builtin_amdgcn_s_setprio(1); MFMA16F(0, aw0, bw1); __builtin_amdgcn_s_setprio(0);
            BAR();
        }
        { // ph3: compute (aw1,bw1); stage B->p0; certify parity 1; prefetch ph4 (p1)
            LGKM0();
            if (nf) STG_B(0, 2 * it + 2);
            __builtin_amdgcn_s_setprio(1); MFMA16F(4, aw1, bw1); __builtin_amdgcn_s_setprio(0);
            if (nf) { asm volatile("s_waitcnt vmcnt(4)" ::: "memory"); }
            else    { asm volatile("s_waitcnt vmcnt(0)" ::: "memory"); }
            LDA4(aw0, 1, 0, 0);
            LDB4(bw0, 1, 0);
            BAR();
        }
        { // ph4: compute (aw0,bw0); stage A->p0; prefetch ph5 A
            LGKM0();
            if (nf) STG_A(0, 2 * it + 2);
            LDA4(aw1, 1, 4, 0);
            __builtin_amdgcn_s_setprio(1); MFMA16F(0, aw0, bw0); __builtin_amdgcn_s_setprio(0);
            BAR();
        }
        { // ph5: compute (aw1,bw0); prefetch ph6 A+B (kk1)
            LGKM0();
            LDA4(aw0, 1, 0, 1);
            LDB4(bw1, 1, 1);
            __builtin_amdgcn_s_setprio(1); MFMA16F(4, aw1, bw0); __builtin_amdgcn_s_setprio(0);
            BAR();
        }
        { // ph6: compute (aw0,bw1); prefetch ph7 A
            LGKM0();
            LDA4(aw1, 1, 4, 1);
            __builtin_amdgcn_s_setprio(1); MFMA16F(0, aw0, bw1); __builtin_amdgcn_s_setprio(0);
            BAR();
        }
        { // ph7: compute (aw1,bw1); stage B->p1; certify parity 0; prefetch next ph0 (p0)
            LGKM0();
            if (nf) STG_B(1, 2 * it + 3);
            __builtin_amdgcn_s_setprio(1); MFMA16F(4, aw1, bw1); __builtin_amdgcn_s_setprio(0);
            if (nf) {
                asm volatile("s_waitcnt vmcnt(4)" ::: "memory");
                LDA4(aw0, 0, 0, 0);
                LDB4(bw0, 0, 0);
            }
            BAR();
        }
    }
#undef STG_A
#undef STG_B
#undef RDA
#undef RDB
#undef LDA4
#undef LDB4
#undef MFMA16F
#undef LGKM0
#undef BAR

    const int sec = n0 >> 11;
#pragma unroll
    for (int mm = 0; mm < 8; ++mm)
#pragma unroll
        for (int nn = 0; nn < 4; ++nn)
#pragma unroll
            for (int j = 0; j < 4; ++j) {
                int grow = m0 + wm * 128 + mm * 16 + hi * 4 + j;   // b*T + t
                int b = grow >> 11, t = grow & 2047;
                int col = n0 + wn * 64 + nn * 16 + ln;
                int c2 = col & 2047;
                int dd = c2 & 127;
                int h = c2 >> 7;
                size_t bh = (size_t)(b * N_HEADS + h);
                if (sec == 0)      o_q[(bh * T_SEQ + t) * HEAD_D + dd] = f2bf(acc[mm][nn][j]);
                else if (sec == 1) o_k[(bh * T_SEQ + t) * HEAD_D + dd] = f2bf(acc[mm][nn][j]);
                else if (sec == 2) o_vt[(bh * HEAD_D + dd) * T_SEQ + t] = f2bf(acc[mm][nn][j]);
                else {
                    float g = acc[mm][nn][j] + b_gate[c2];
                    g = 1.0f / (1.0f + __expf(-g));
                    o_g[(size_t)grow * D_MODEL + c2] = f2bf(g);
                }
            }
}

// ---------- out GEMM: 128x128, BK=64, dbuf + counted vmcnt(8) (R19/R21 exact) ----------
template <int RGN_M, int RGN_N>
__global__ __launch_bounds__(256) void gemm_bt(
    const ushort_t* __restrict__ A, const ushort_t* __restrict__ Bt,
    int N, int K, float* __restrict__ o_f32)
{
    __shared__ ushort_t As[2][128 * 64];
    __shared__ ushort_t Bs[2][128 * 64];
    const int tid = threadIdx.x;
    const int wid = tid >> 6, l = tid & 63;
    const int ln = l & 15, hi = l >> 4;
    const int lnx = (ln & 7) << 4;
    const int wm = wid >> 1, wn = wid & 1;

    const int lin = blockIdx.x;
    const int r = lin & 7, w = lin >> 3;
    const int bm = (r >> 2) * RGN_M + w / RGN_N;
    const int bn = (r & 3) * RGN_N + w % RGN_N;
    const int m0 = bm * 128, n0 = bn * 128;

    f32x4 acc[4][4];
#pragma unroll
    for (int m = 0; m < 4; ++m)
#pragma unroll
        for (int n = 0; n < 4; ++n) acc[m][n] = (f32x4){0.f, 0.f, 0.f, 0.f};

    const int srow = tid >> 3;
    const int scol = ((tid & 7) ^ (srow & 7)) << 3;
    const ushort_t* Ag = A + (size_t)(m0 + srow) * K + scol;
    const ushort_t* Bg = Bt + (size_t)(n0 + srow) * K + scol;

#define GSTAGE(ktb, Ad, Bd)                                                   \
    {                                                                         \
        _Pragma("unroll")                                                     \
        for (int i_ = 0; i_ < 4; ++i_) {                                      \
            gload16(Ag + (size_t)(i_ * 32) * K + (ktb), (Ad) + i_ * 2048);    \
            gload16(Bg + (size_t)(i_ * 32) * K + (ktb), (Bd) + i_ * 2048);    \
        }                                                                     \
    }

    const int nkt = K >> 6;
    int cur = 0;
    GSTAGE(0, As[0] + wid * 512, Bs[0] + wid * 512);

    for (int t = 0; t < nkt; ++t) {
        if (t + 1 < nkt) {
            GSTAGE((t + 1) << 6, As[cur ^ 1] + wid * 512, Bs[cur ^ 1] + wid * 512);
            asm volatile("s_waitcnt vmcnt(8)" ::: "memory");
        } else {
            asm volatile("s_waitcnt vmcnt(0)" ::: "memory");
        }
        __builtin_amdgcn_s_barrier();

        const char* Ab_ = (const char*)As[cur];
        const char* Bb_ = (const char*)Bs[cur];
        __builtin_amdgcn_s_setprio(1);
#pragma unroll
        for (int kk = 0; kk < 2; ++kk) {
            bf16x8 af[4], bfg[4];
#pragma unroll
            for (int m = 0; m < 4; ++m)
                af[m] = *(const bf16x8*)(Ab_ + (((wm * 64 + m * 16 + ln) << 7) +
                                                (((kk << 6) + (hi << 4)) ^ lnx)));
#pragma unroll
            for (int n = 0; n < 4; ++n)
                bfg[n] = *(const bf16x8*)(Bb_ + (((wn * 64 + n * 16 + ln) << 7) +
                                                 (((kk << 6) + (hi << 4)) ^ lnx)));
#pragma unroll
            for (int m = 0; m < 4; ++m)
#pragma unroll
                for (int n = 0; n < 4; ++n)
                    acc[m][n] = __builtin_amdgcn_mfma_f32_16x16x32_bf16(af[m], bfg[n], acc[m][n], 0, 0, 0);
        }
        __builtin_amdgcn_s_setprio(0);
        asm volatile("s_waitcnt lgkmcnt(0)" ::: "memory");
        __builtin_amdgcn_s_barrier();
        cur ^= 1;
    }
#undef GSTAGE

#pragma unroll
    for (int m = 0; m < 4; ++m)
#pragma unroll
        for (int n = 0; n < 4; ++n)
#pragma unroll
            for (int j = 0; j < 4; ++j) {
                int grow = m0 + wm * 64 + m * 16 + hi * 4 + j;
                int gcol = n0 + wn * 64 + n * 16 + ln;
                o_f32[(size_t)grow * N + gcol] = acc[m][n][j];
            }
}

// ---------- RMSNorm + RoPE, in place on q and k [B,H,T,128] ----------
__global__ __launch_bounds__(256) void rmsrope_kernel(ushort_t* __restrict__ qb, ushort_t* __restrict__ kb) {
    int wid = threadIdx.x >> 6, l = threadIdx.x & 63;
    int row = blockIdx.x * 4 + wid;          // (b*H + h)*T + t
    int t = row & (T_SEQ - 1);
    size_t base = (size_t)row * HEAD_D;

    float ang = (float)t * expf(-(float)l * 0.14391156f);
    float sv, cv;
    sincosf(ang, &sv, &cv);

    float a = bf2f(qb[base + l]), b = bf2f(qb[base + 64 + l]);
    float ss = a * a + b * b;
#pragma unroll
    for (int d = 1; d < 64; d <<= 1) ss += __shfl_xor(ss, d);
    float r = rsqrtf(ss * (1.0f / 128.0f) + 1e-6f);
    a *= r; b *= r;
    qb[base + l]      = f2bf(a * cv - b * sv);
    qb[base + 64 + l] = f2bf(a * sv + b * cv);

    a = bf2f(kb[base + l]); b = bf2f(kb[base + 64 + l]);
    ss = a * a + b * b;
#pragma unroll
    for (int d = 1; d < 64; d <<= 1) ss += __shfl_xor(ss, d);
    r = rsqrtf(ss * (1.0f / 128.0f) + 1e-6f);
    a *= r; b *= r;
    kb[base + l]      = f2bf(a * cv - b * sv);
    kb[base + 64 + l] = f2bf(a * sv + b * cv);
}

// ---------- causal flash attention v7 (R10..R22 passing version, unchanged) ----------
__global__ __launch_bounds__(256) void flash_kernel(
    const ushort_t* __restrict__ qb, const ushort_t* __restrict__ kb,
    const ushort_t* __restrict__ vt, const ushort_t* __restrict__ g_b,
    ushort_t* __restrict__ y_b)
{
    const int bh = blockIdx.x, bxp = blockIdx.y;
    const int tid = threadIdx.x;
    const int wid = tid >> 6, l = tid & 63;
    const int ln = l & 15, hi = l >> 4;
    const int lnx = (ln & 7) << 4;

    const ushort_t* Q  = qb + (size_t)bh * T_SEQ * HEAD_D;
    const ushort_t* Kp = kb + (size_t)bh * T_SEQ * HEAD_D;
    const ushort_t* Vp = vt + (size_t)bh * HEAD_D * T_SEQ;

    __shared__ ushort_t Ks[4][64 * 128];
    __shared__ ushort_t Vs[4][128 * 64];
    __shared__ ushort_t p_all[4][32][72];
    ushort_t (*p_lds)[72] = p_all[wid];

    const float scale_log2 = 0.12752059520313818f;
    const int bb = bh >> 4, h = bh & 15;

    int s_off[4], s_ksrc[4], s_vrow[4], s_vcol[4];
#pragma unroll
    for (int i = 0; i < 4; ++i) {
        int off = (i * 256 + tid) * 16;
        s_off[i] = (i * 4 + wid) * 512;
        int krow = off >> 8;
        s_ksrc[i] = off ^ ((krow & 7) << 4);
        int vrow = off >> 7;
        s_vrow[i] = vrow;
        s_vcol[i] = ((off & 127) ^ ((vrow & 7) << 4)) >> 1;
    }

#define STAGE(kvbase, Kd, Vd)                                                            \
    {                                                                                    \
        _Pragma("unroll")                                                                \
        for (int i_ = 0; i_ < 4; ++i_) {                                                 \
            gload16((const ushort_t*)((const char*)(Kp + (size_t)(kvbase) * HEAD_D) +    \
                                      s_ksrc[i_]), (Kd) + s_off[i_]);                    \
            gload16(Vp + (size_t)s_vrow[i_] * T_SEQ + (kvbase) + s_vcol[i_],             \
                    (Vd) + s_off[i_]);                                                   \
        }                                                                                \
    }

    for (int pass = 0; pass < 2; ++pass) {
        const int qt = pass ? (15 - bxp) : bxp;
        const int q0w = qt * 128 + wid * 32;
        const int nt = 2 * qt + 2;

        bf16x8 qf[2][4];
#pragma unroll
        for (int m = 0; m < 2; ++m)
#pragma unroll
            for (int kk = 0; kk < 4; ++kk)
                qf[m][kk] = *(const bf16x8*)(Q + (size_t)(q0w + m * 16 + ln) * HEAD_D + kk * 32 + hi * 8);

        f32x4 acc_o[2][8];
#pragma unroll
        for (int m = 0; m < 2; ++m)
#pragma unroll
            for (int nd = 0; nd < 8; ++nd) acc_o[m][nd] = (f32x4){0.f, 0.f, 0.f, 0.f};
        float rl[2][4];
#pragma unroll
        for (int m = 0; m < 2; ++m)
#pragma unroll
            for (int j = 0; j < 4; ++j) rl[m][j] = 0.f;

        ushort_t *Ka = Ks[0], *Kb = Ks[1], *Kc = Ks[2], *Kd4 = Ks[3];
        ushort_t *Va = Vs[0], *Vb = Vs[1], *Vc = Vs[2], *Vd4 = Vs[3];

        STAGE(0, Ka, Va);
        STAGE(64, Kb, Vb);

        for (int t = 0; t < nt; ++t) {
            const int kv0 = t * 64;
            if (t + 2 < nt) {
                STAGE(kv0 + 128, Kc, Vc);
                asm volatile("s_waitcnt vmcnt(16)" ::: "memory");
            } else if (t + 1 < nt) {
                asm volatile("s_waitcnt vmcnt(8)" ::: "memory");
            } else {
                asm volatile("s_waitcnt vmcnt(0)" ::: "memory");
            }
            SBAR0();
            __builtin_amdgcn_s_barrier();
            SBAR0();

            if (kv0 <= q0w + 31) {
                const ushort_t* Ksc = Ka;
                const ushort_t* Vsc = Va;

                f32x4 sa[2][4];
#pragma unroll
                for (int m = 0; m < 2; ++m)
#pragma unroll
                    for (int n = 0; n < 4; ++n) sa[m][n] = (f32x4){0.f, 0.f, 0.f, 0.f};
#pragma unroll
                for (int kk = 0; kk < 4; ++kk) {
                    bf16x8 kf[4];
#pragma unroll
                    for (int n = 0; n < 4; ++n)
                        kf[n] = *(const bf16x8*)((const char*)Ksc +
                                 ((((n * 16 + ln) << 8) + (kk << 6) + (hi << 4)) ^ lnx));
#pragma unroll
                    for (int m = 0; m < 2; ++m)
#pragma unroll
                        for (int n = 0; n < 4; ++n)
                            sa[m][n] = __builtin_amdgcn_mfma_f32_16x16x32_bf16(qf[m][kk], kf[n], sa[m][n], 0, 0, 0);
                }

                const bool partial = (kv0 + 63 > q0w);
                if (partial) {
#pragma unroll
                    for (int m = 0; m < 2; ++m)
#pragma unroll
                        for (int n = 0; n < 4; ++n)
#pragma unroll
                            for (int j = 0; j < 4; ++j) {
                                int kv = kv0 + n * 16 + ln;
                                int qrow = q0w + m * 16 + hi * 4 + j;
                                float v = (kv <= qrow) ? sa[m][n][j] * scale_log2 : -1e30f;
                                float p = __builtin_amdgcn_exp2f(v);
                                rl[m][j] += p;
                                p_lds[m * 16 + hi * 4 + j][n * 16 + ln] = f2bf(p);
                            }
                } else {
#pragma unroll
                    for (int m = 0; m < 2; ++m)
#pragma unroll
                        for (int n = 0; n < 4; ++n)
#pragma unroll
                            for (int j = 0; j < 4; ++j) {
                                float p = __builtin_amdgcn_exp2f(sa[m][n][j] * scale_log2);
                                rl[m][j] += p;
                                p_lds[m * 16 + hi * 4 + j][n * 16 + ln] = f2bf(p);
                            }
                }
                asm volatile("s_waitcnt lgkmcnt(0)" ::: "memory");
                SBAR0();

                const bool skipB = (kv0 + 32 > q0w + 31);
                bf16x8 pf[2][2];
#pragma unroll
                for (int m = 0; m < 2; ++m)
#pragma unroll
                    for (int kk2 = 0; kk2 < 2; ++kk2)
                        pf[m][kk2] = *(const bf16x8*)(&p_lds[m * 16 + ln][kk2 * 32 + hi * 8]);
#pragma unroll
                for (int nd = 0; nd < 8; ++nd) {
                    bf16x8 vf = *(const bf16x8*)((const char*)Vsc +
                                 ((((nd * 16 + ln) << 7) + (hi << 4)) ^ lnx));
                    acc_o[0][nd] = __builtin_amdgcn_mfma_f32_16x16x32_bf16(pf[0][0], vf, acc_o[0][nd], 0, 0, 0);
                    acc_o[1][nd] = __builtin_amdgcn_mfma_f32_16x16x32_bf16(pf[1][0], vf, acc_o[1][nd], 0, 0, 0);
                }
                if (!skipB) {
#pragma unroll
                    for (int nd = 0; nd < 8; ++nd) {
                        bf16x8 vf = *(const bf16x8*)((const char*)Vsc +
                                     ((((nd * 16 + ln) << 7) + 64 + (hi << 4)) ^ lnx));
                        acc_o[0][nd] = __builtin_amdgcn_mfma_f32_16x16x32_bf16(pf[0][1], vf, acc_o[0][nd], 0, 0, 0);
                        acc_o[1][nd] = __builtin_amdgcn_mfma_f32_16x16x32_bf16(pf[1][1], vf, acc_o[1][nd], 0, 0, 0);
                    }
                }
            }
            asm volatile("s_waitcnt lgkmcnt(0)" ::: "memory");
            SBAR0();
            __builtin_amdgcn_s_barrier();
            SBAR0();
            ushort_t* tK = Ka; Ka = Kb; Kb = Kc; Kc = Kd4; Kd4 = tK;
            ushort_t* tV = Va; Va = Vb; Vb = Vc; Vc = Vd4; Vd4 = tV;
        }

#pragma unroll
        for (int d = 1; d < 16; d <<= 1)
#pragma unroll
            for (int m = 0; m < 2; ++m)
#pragma unroll
                for (int j = 0; j < 4; ++j)
                    rl[m][j] += __shfl_xor(rl[m][j], d);

#pragma unroll
        for (int m = 0; m < 2; ++m)
#pragma unroll
            for (int j = 0; j < 4; ++j) {
                float inv = 1.0f / rl[m][j];
                int tr = q0w + m * 16 + hi * 4 + j;
#pragma unroll
                for (int nd = 0; nd < 8; ++nd) {
                    size_t idx = ((size_t)(bb * T_SEQ + tr)) * D_MODEL + h * HEAD_D + nd * 16 + ln;
                    y_b[idx] = f2bf(acc_o[m][nd][j] * inv * bf2f(g_b[idx]));
                }
            }
    }
#undef STAGE
}

// ---------- launch ----------
extern "C" void kernel_launch(void* const* d_in, const int* in_sizes, int n_in,
                              void* d_out, int out_size, void* d_ws, size_t ws_size,
                              hipStream_t stream) {
    const float* x      = (const float*)d_in[0];
    const float* W_qkv  = (const float*)d_in[1];
    const float* W_out  = (const float*)d_in[2];
    const float* W_gate = (const float*)d_in[3];
    const float* b_gate = (const float*)d_in[4];
    float* out = (float*)d_out;

    char* ws = (char*)d_ws;
    size_t off = 0;
    ushort_t* xb     = (ushort_t*)(ws + off); off += (size_t)M_ROWS * D_MODEL * 2;
    ushort_t* wqgT   = (ushort_t*)(ws + off); off += (size_t)4 * D_MODEL * D_MODEL * 2;
    ushort_t* woutT  = (ushort_t*)(ws + off); off += (size_t)D_MODEL * D_MODEL * 2;
    ushort_t* q_b    = (ushort_t*)(ws + off); off += (size_t)M_ROWS * D_MODEL * 2;
    ushort_t* k_b    = (ushort_t*)(ws + off); off += (size_t)M_ROWS * D_MODEL * 2;
    ushort_t* v_t    = (ushort_t*)(ws + off); off += (size_t)M_ROWS * D_MODEL * 2;
    ushort_t* g_b    = (ushort_t*)(ws + off); off += (size_t)M_ROWS * D_MODEL * 2;
    ushort_t* y_b    = (ushort_t*)(ws + off); off += (size_t)M_ROWS * D_MODEL * 2;

    prep_kernel<<<8192 + 192 * 64 + 64 * 64 + 64 * 64, 256, 0, stream>>>(
        x, xb, W_qkv, W_gate, W_out, wqgT, woutT);
    gemm256_qkvg<<<512, 512, 0, stream>>>(xb, wqgT, q_b, k_b, v_t, b_gate, g_b);
    rmsrope_kernel<<<16384, 256, 0, stream>>>(q_b, k_b);
    flash_kernel<<<dim3(32, 8), 256, 0, stream>>>(q_b, k_b, v_t, g_b, y_b);
    gemm_bt<16, 4><<<512, 256, 0, stream>>>(y_b, woutT, D_MODEL, D_MODEL, out);
}